// Round 10
// baseline (1037.464 us; speedup 1.0000x reference)
//
#include <hip/hip_runtime.h>
#include <hip/hip_cooperative_groups.h>
#include <math.h>

#define D_MODEL 1024
#define D_INNER 2048
#define DPROJ   96      // DT_RANK + 2*D_STATE
#define DT_RANK 64
#define NSTATE  16
#define SEQ     2048
#define CL      16      // chunk length for scan
#define NCH     (SEQ/CL)            // 128
#define SCAN_SEGS 4
#define SCAN_CPS  (NCH / SCAN_SEGS) // 32 chunks per segment-lane
#define LOG2E   1.44269504088896340736f

typedef unsigned short ushort_t;
typedef short v8s __attribute__((ext_vector_type(8)));
typedef float v4f __attribute__((ext_vector_type(4)));
typedef __attribute__((address_space(3))) unsigned int as3_u32;
typedef __attribute__((address_space(1))) unsigned int as1_u32;

__device__ __forceinline__ float silu_f(float x) { return x / (1.f + expf(-x)); }

__device__ __forceinline__ ushort_t f2bf(float f) {
  union { float f; unsigned u; } x; x.f = f;
  unsigned r = x.u + 0x7fffu + ((x.u >> 16) & 1u);  // RNE; inputs finite
  return (ushort_t)(r >> 16);
}
__device__ __forceinline__ float bf2f(ushort_t b) {
  union { unsigned u; float f; } x; x.u = ((unsigned)b) << 16; return x.f;
}

// async global->LDS, 16B per lane; lds dest = wave-uniform base + lane*16
__device__ __forceinline__ void gl_lds16(const ushort_t* g, ushort_t* l) {
  __builtin_amdgcn_global_load_lds((const as1_u32*)g, (as3_u32*)l, 16, 0, 0);
}

// res = a (+a2+a3+a4) (+ b); xn = rmsnorm(res)*w -> f32 (xnf) and/or bf16 (xnb)
__global__ __launch_bounds__(256) void addrms_kernel(
    const float* __restrict__ a, const float* __restrict__ a2,
    const float* __restrict__ a3, const float* __restrict__ a4,
    const float* __restrict__ b,
    const float* __restrict__ w, float* __restrict__ res_out,
    float* __restrict__ xnf, ushort_t* __restrict__ xnb) {
  int t = blockIdx.x;
  int tid = threadIdx.x;
  float v[4];
  float ss = 0.f;
#pragma unroll
  for (int j = 0; j < 4; ++j) {
    int dcol = tid + j * 256;
    size_t off = (size_t)t * D_MODEL + dcol;
    float x = a[off];
    if (a2) x += a2[off];
    if (a3) x += a3[off];
    if (a4) x += a4[off];
    if (b) x += b[off];
    v[j] = x;
    ss += x * x;
  }
#pragma unroll
  for (int off = 32; off > 0; off >>= 1) ss += __shfl_down(ss, off);
  __shared__ float red[4];
  __shared__ float rmsv;
  int wid = tid >> 6, lane = tid & 63;
  if (lane == 0) red[wid] = ss;
  __syncthreads();
  if (tid == 0) {
    float s = red[0] + red[1] + red[2] + red[3];
    rmsv = rsqrtf(s / (float)D_MODEL + 1e-5f);
  }
  __syncthreads();
  float r = rmsv;
#pragma unroll
  for (int j = 0; j < 4; ++j) {
    int dcol = tid + j * 256;
    if (res_out) res_out[(size_t)t * D_MODEL + dcol] = v[j];
    float xn = v[j] * r * w[dcol];
    if (xnf) xnf[(size_t)t * D_MODEL + dcol] = xn;
    if (xnb) xnb[(size_t)t * D_MODEL + dcol] = f2bf(xn);
  }
}

// single-dispatch f32->bf16 of all 4 weight tensors (both layers each)
__global__ __launch_bounds__(256) void f2bf_all_kernel(
    const float* __restrict__ s0, ushort_t* __restrict__ d0, int n0,
    const float* __restrict__ s1, ushort_t* __restrict__ d1, int n1,
    const float* __restrict__ s2, ushort_t* __restrict__ d2, int n2,
    const float* __restrict__ s3, ushort_t* __restrict__ d3, int n3) {
  int j = blockIdx.x * 256 + threadIdx.x;
  const float* s; ushort_t* d;
  if (j < n0) { s = s0; d = d0; }
  else {
    j -= n0;
    if (j < n1) { s = s1; d = d1; }
    else {
      j -= n1;
      if (j < n2) { s = s2; d = d2; }
      else {
        j -= n2;
        if (j >= n3) return;
        s = s3; d = d3;
      }
    }
  }
  float4 v = ((const float4*)s)[j];
  ushort4 o;
  o.x = f2bf(v.x); o.y = f2bf(v.y); o.z = f2bf(v.z); o.w = f2bf(v.w);
  ((ushort4*)d)[j] = o;
}

// ------------- bf16 MFMA GEMM (NT): C[m,n] = sum_k A[m,k]*B[n,k] -------------
// m97 structure + double-buffered prefetch; one __syncthreads per K-step.
// EPI: 0 = f32 out, 1 = softplus(acc+bias[col]) -> bf16, 2 = bf16,
//      3 = pack( bf16(softplus(acc+bias)) | upack[idx]<<16 ) -> uint out.
template <int SPLITK, bool CLAMPN, int EPI>
__global__ __launch_bounds__(256) void gemm_bt(
    const ushort_t* __restrict__ A, const ushort_t* __restrict__ B,
    void* __restrict__ Cv, const float* __restrict__ bias,
    const ushort_t* __restrict__ upack,
    int M, int N, int K, int lda, int ldb, int ldc) {
  __shared__ ushort_t As[2][128 * 32];
  __shared__ ushort_t Bs[2][128 * 32];
  int tid = threadIdx.x;
  int bm = blockIdx.y * 128;
  int bn = blockIdx.x * 128;
  int kchunk = K / SPLITK;
  int k0 = blockIdx.z * kchunk;
  int nk = kchunk / 32;

  int lane = tid & 63, wid = tid >> 6;
  int wr = wid >> 1, wc = wid & 1;
  int lr = lane & 15;
  int ko = (lane >> 4) * 8;

  int rs0 = wid * 16 + (lane >> 2);
  int segc = (lane & 3) * 8;

  auto stage = [&](int buf, int kt) {
#pragma unroll
    for (int s = 0; s < 2; ++s) {
      int r = s * 64 + rs0;
      int cc = kt + segc;
      gl_lds16(A + (size_t)(bm + r) * lda + cc, &As[buf][s * 2048 + wid * 512]);
      int bc = bn + r;
      if (CLAMPN) bc = min(bc, N - 1);   // in-bounds; junk cols never stored
      gl_lds16(B + (size_t)bc * ldb + cc, &Bs[buf][s * 2048 + wid * 512]);
    }
  };

  v4f acc[4][4] = {};

  stage(0, k0);
  __syncthreads();
  int cur = 0;
  for (int it = 0; it < nk; ++it) {
    if (it + 1 < nk) stage(cur ^ 1, k0 + (it + 1) * 32);
    v8s a[4], b[4];
#pragma unroll
    for (int m = 0; m < 4; ++m)
      a[m] = *(const v8s*)&As[cur][(wr * 64 + m * 16 + lr) * 32 + ko];
#pragma unroll
    for (int n = 0; n < 4; ++n)
      b[n] = *(const v8s*)&Bs[cur][(wc * 64 + n * 16 + lr) * 32 + ko];
#pragma unroll
    for (int m = 0; m < 4; ++m)
#pragma unroll
      for (int n = 0; n < 4; ++n)
        acc[m][n] = __builtin_amdgcn_mfma_f32_16x16x32_bf16(a[m], b[n], acc[m][n], 0, 0, 0);
    __syncthreads();
    cur ^= 1;
  }

  float* Cf = (float*)Cv;
  ushort_t* Cb = (ushort_t*)Cv;
  unsigned* Cu = (unsigned*)Cv;
  if (SPLITK > 1) Cf += (size_t)blockIdx.z * (size_t)M * (size_t)ldc;

#pragma unroll
  for (int m = 0; m < 4; ++m) {
#pragma unroll
    for (int n = 0; n < 4; ++n) {
      int gc = bn + wc * 64 + n * 16 + lr;
      if (gc >= N) continue;
      int gr0 = bm + wr * 64 + m * 16 + (lane >> 4) * 4;
      float bv = (EPI == 1 || EPI == 3) ? bias[gc] : 0.f;
#pragma unroll
      for (int j = 0; j < 4; ++j) {
        float val = acc[m][n][j];
        size_t idx = (size_t)(gr0 + j) * ldc + gc;
        if (EPI == 0) {
          Cf[idx] = val;
        } else if (EPI == 1) {
          float x = val + bv;
          x = fmaxf(x, 0.f) + log1pf(expf(-fabsf(x)));
          Cb[idx] = f2bf(x);
        } else if (EPI == 2) {
          Cb[idx] = f2bf(val);
        } else {
          float x = val + bv;
          x = fmaxf(x, 0.f) + log1pf(expf(-fabsf(x)));
          Cu[idx] = (unsigned)f2bf(x) | ((unsigned)upack[idx] << 16);
        }
      }
    }
  }
}

// out[idx] = sum_p part[idx + p*sz]; optional bf16 mirror
__global__ __launch_bounds__(256) void reduceN_kernel(
    const float* __restrict__ part, float* __restrict__ out,
    ushort_t* __restrict__ outb, int sz, int nparts) {
  int idx = blockIdx.x * 256 + threadIdx.x;
  if (idx >= sz) return;
  float s = 0.f;
  for (int p = 0; p < nparts; ++p) s += part[idx + (size_t)p * sz];
  out[idx] = s;
  if (outb) outb[idx] = f2bf(s);
}

// depthwise causal conv (k=4) + silu, bf16 in (xz) -> bf16 out; 4 channels/thread
__global__ __launch_bounds__(256) void conv_silu_kernel(
    const ushort_t* __restrict__ xzb, const float* __restrict__ cw,
    const float* __restrict__ cb, ushort_t* __restrict__ xcb) {
  int idx = blockIdx.x * 256 + threadIdx.x;   // over SEQ * (D_INNER/4)
  int t = idx >> 9;
  int c = (idx & 511) * 4;
  float acc[4];
  float4 cbv = *(const float4*)&cb[c];
  acc[0] = cbv.x; acc[1] = cbv.y; acc[2] = cbv.z; acc[3] = cbv.w;
  float4 wv[4];
#pragma unroll
  for (int i = 0; i < 4; ++i) wv[i] = *(const float4*)&cw[(c + i) * 4];
#pragma unroll
  for (int k = 0; k < 4; ++k) {
    int ts = t - 3 + k;
    if (ts < 0) continue;
    ushort4 x = *(const ushort4*)&xzb[(size_t)ts * 4096 + c];
    acc[0] = fmaf(bf2f(x.x), ((const float*)&wv[0])[k], acc[0]);
    acc[1] = fmaf(bf2f(x.y), ((const float*)&wv[1])[k], acc[1]);
    acc[2] = fmaf(bf2f(x.z), ((const float*)&wv[2])[k], acc[2]);
    acc[3] = fmaf(bf2f(x.w), ((const float*)&wv[3])[k], acc[3]);
  }
  ushort4 o;
  o.x = f2bf(silu_f(acc[0]));
  o.y = f2bf(silu_f(acc[1]));
  o.z = f2bf(silu_f(acc[2]));
  o.w = f2bf(silu_f(acc[3]));
  *(ushort4*)&xcb[(size_t)t * D_INNER + c] = o;
}

// Pass A: per-chunk cumulative dA product + local end state (h0 = 0).
__global__ __launch_bounds__(256) void scan_passA_kernel(
    const unsigned* __restrict__ dtu, const float* __restrict__ dbc,
    const float* __restrict__ A_log,
    float* __restrict__ aprod, float* __restrict__ hend) {
  __shared__ float Bsh[CL][16];
  int c = blockIdx.x;
  int d = blockIdx.y * 256 + threadIdx.x;
  int t0 = c * CL;
  {
    int j = threadIdx.x;
    if (j < CL * 4) {
      int r = j >> 2, col = (j & 3) * 4;
      *(float4*)&Bsh[r][col] = *(const float4*)&dbc[(size_t)(t0 + r) * DPROJ + DT_RANK + col];
    }
  }
  float Av[NSTATE], h[NSTATE], ap[NSTATE];
#pragma unroll
  for (int n = 0; n < NSTATE; ++n) {
    Av[n] = -expf(A_log[(size_t)d * NSTATE + n]) * LOG2E;
    h[n] = 0.f;
    ap[n] = 1.f;
  }
  __syncthreads();
#pragma unroll 2
  for (int tt = 0; tt < CL; ++tt) {
    unsigned p = dtu[(size_t)(t0 + tt) * D_INNER + d];
    float dtv = bf2f((ushort_t)(p & 0xffffu));
    float uv  = bf2f((ushort_t)(p >> 16));
    float du = dtv * uv;
#pragma unroll
    for (int n = 0; n < NSTATE; ++n) {
      float dA = exp2f(dtv * Av[n]);
      h[n] = fmaf(dA, h[n], du * Bsh[tt][n]);
      ap[n] *= dA;
    }
  }
  size_t base = ((size_t)c * D_INNER + d) * NSTATE;
#pragma unroll
  for (int n = 0; n < NSTATE; ++n) {
    aprod[base + n] = ap[n];
    hend[base + n] = h[n];
  }
}

// Pass B: carry across 128 chunks (512 blocks; 4 lanes x 32 chunks per chain).
__global__ __launch_bounds__(256) void scan_passB_kernel(
    const float* __restrict__ aprod, float* __restrict__ hend_hin) {
  int tid = threadIdx.x;
  int lane = tid & 63;
  int wave = tid >> 6;
  int seg = lane >> 4;                       // 0..3
  int chain = blockIdx.x * 64 + wave * 16 + (lane & 15);
  const size_t stride = (size_t)D_INNER * NSTATE;
  float a[SCAN_CPS], e[SCAN_CPS];
  float P = 1.f, E = 0.f;
  int c0 = seg * SCAN_CPS;
#pragma unroll
  for (int j = 0; j < SCAN_CPS; ++j) {
    a[j] = aprod[(size_t)(c0 + j) * stride + chain];
    e[j] = hend_hin[(size_t)(c0 + j) * stride + chain];
    E = fmaf(a[j], E, e[j]);
    P *= a[j];
  }
#pragma unroll
  for (int dstep = 1; dstep < SCAN_SEGS; dstep <<= 1) {
    float Pp = __shfl_up(P, dstep * 16);
    float Ep = __shfl_up(E, dstep * 16);
    if (seg >= dstep) { E = fmaf(P, Ep, E); P *= Pp; }
  }
  float Ex = __shfl_up(E, 16);
  if (seg == 0) Ex = 0.f;
  float h = Ex;
#pragma unroll
  for (int j = 0; j < SCAN_CPS; ++j) {
    hend_hin[(size_t)(c0 + j) * stride + chain] = h;
    h = fmaf(a[j], h, e[j]);
  }
}

// Pass C: rescan from hin; y = (scan + u*D) * silu(z) -> bf16.
__global__ __launch_bounds__(256) void scan_passC_kernel(
    const unsigned* __restrict__ dtu, const float* __restrict__ dbc,
    const float* __restrict__ A_log, const float* __restrict__ Dp,
    const ushort_t* __restrict__ xzb, const float* __restrict__ hin,
    ushort_t* __restrict__ yb) {
  __shared__ float BCsh[CL][32];   // [tt][0..15]=B, [16..31]=C
  int c = blockIdx.x;
  int d = blockIdx.y * 256 + threadIdx.x;
  int t0 = c * CL;
  {
    int j = threadIdx.x;
    if (j < CL * 8) {
      int r = j >> 3, col = (j & 7) * 4;
      *(float4*)&BCsh[r][col] = *(const float4*)&dbc[(size_t)(t0 + r) * DPROJ + DT_RANK + col];
    }
  }
  float Av[NSTATE], h[NSTATE];
  size_t base = ((size_t)c * D_INNER + d) * NSTATE;
#pragma unroll
  for (int n = 0; n < NSTATE; ++n) {
    Av[n] = -expf(A_log[(size_t)d * NSTATE + n]) * LOG2E;
    h[n] = hin[base + n];
  }
  float Dv = Dp[d];
  __syncthreads();
#pragma unroll 2
  for (int tt = 0; tt < CL; ++tt) {
    unsigned p = dtu[(size_t)(t0 + tt) * D_INNER + d];
    float dtv = bf2f((ushort_t)(p & 0xffffu));
    float uv  = bf2f((ushort_t)(p >> 16));
    float du = dtv * uv;
    float yv = 0.f;
#pragma unroll
    for (int n = 0; n < NSTATE; ++n) {
      float dA = exp2f(dtv * Av[n]);
      h[n] = fmaf(dA, h[n], du * BCsh[tt][n]);
      yv = fmaf(h[n], BCsh[tt][16 + n], yv);
    }
    float zv = bf2f(xzb[(size_t)(t0 + tt) * 4096 + D_INNER + d]);
    yb[(size_t)(t0 + tt) * D_INNER + d] = f2bf((yv + uv * Dv) * silu_f(zv));
  }
}

// ---------------- fused selective scan (cooperative, 512 blocks = 2/CU) -------
// Each block: 2 chunks x 256 d-channels. Phase A -> grid.sync -> Phase B
// (identical layout to scan_passB, 512 blocks) -> grid.sync -> Phase C.
// dtu/Av/BCsh persist in registers/LDS from A to C.
__global__ __launch_bounds__(256, 2) void scan_fused_kernel(
    const unsigned* __restrict__ dtu, const float* __restrict__ dbc,
    const float* __restrict__ A_log, const float* __restrict__ Dp,
    const ushort_t* __restrict__ xzb, float* __restrict__ aprod,
    float* __restrict__ hend, ushort_t* __restrict__ yb) {
  cooperative_groups::grid_group grid = cooperative_groups::this_grid();
  int tid = threadIdx.x;
  int cg = blockIdx.x >> 3;          // 0..63 (2 chunks each)
  int d = (blockIdx.x & 7) * 256 + tid;
  __shared__ float BCsh[2][CL][32];  // [cc][tt][0..15]=B, [16..31]=C
  {
    int j = tid;                     // 2*CL*32/4 = 256 float4 slots
    int cc = j >> 7;
    int r = (j >> 3) & 15;
    int col = (j & 7) * 4;
    int t0s = (cg * 2 + cc) * CL;
    *(float4*)&BCsh[cc][r][col] =
        *(const float4*)&dbc[(size_t)(t0s + r) * DPROJ + DT_RANK + col];
  }
  float Av[NSTATE];
  unsigned dup[2][CL];
#pragma unroll
  for (int n = 0; n < NSTATE; ++n)
    Av[n] = -expf(A_log[(size_t)d * NSTATE + n]) * LOG2E;
  __syncthreads();

  // Phase A (full unroll: dup must stay register-resident)
#pragma unroll
  for (int cc = 0; cc < 2; ++cc) {
    int c = cg * 2 + cc;
    int t0 = c * CL;
    float h[NSTATE], ap[NSTATE];
#pragma unroll
    for (int n = 0; n < NSTATE; ++n) { h[n] = 0.f; ap[n] = 1.f; }
#pragma unroll
    for (int tt = 0; tt < CL; ++tt) {
      unsigned p = dtu[(size_t)(t0 + tt) * D_INNER + d];
      dup[cc][tt] = p;
      float dtv = bf2f((ushort_t)(p & 0xffffu));
      float uv  = bf2f((ushort_t)(p >> 16));
      float du = dtv * uv;
#pragma unroll
      for (int n = 0; n < NSTATE; ++n) {
        float dA = exp2f(dtv * Av[n]);
        h[n] = fmaf(dA, h[n], du * BCsh[cc][tt][n]);
        ap[n] *= dA;
      }
    }
    size_t base = ((size_t)c * D_INNER + d) * NSTATE;
#pragma unroll
    for (int n = 0; n < NSTATE; ++n) {
      aprod[base + n] = ap[n];
      hend[base + n] = h[n];
    }
  }

  grid.sync();

  // Phase B: carry across 128 chunks; 4 lanes x 32 chunks per chain
  {
    int lane = tid & 63, wave = tid >> 6;
    int seg = lane >> 4;
    int chain = blockIdx.x * 64 + wave * 16 + (lane & 15);
    const size_t stride = (size_t)D_INNER * NSTATE;
    float a[SCAN_CPS], e[SCAN_CPS];
    float P = 1.f, E = 0.f;
    int c0 = seg * SCAN_CPS;
#pragma unroll
    for (int j = 0; j < SCAN_CPS; ++j) {
      a[j] = aprod[(size_t)(c0 + j) * stride + chain];
      e[j] = hend[(size_t)(c0 + j) * stride + chain];
      E = fmaf(a[j], E, e[j]);
      P *= a[j];
    }
#pragma unroll
    for (int dstep = 1; dstep < SCAN_SEGS; dstep <<= 1) {
      float Pp = __shfl_up(P, dstep * 16);
      float Ep = __shfl_up(E, dstep * 16);
      if (seg >= dstep) { E = fmaf(P, Ep, E); P *= Pp; }
    }
    float Ex = __shfl_up(E, 16);
    if (seg == 0) Ex = 0.f;
    float hh = Ex;
#pragma unroll
    for (int j = 0; j < SCAN_CPS; ++j) {
      hend[(size_t)(c0 + j) * stride + chain] = hh;   // h_in per chunk
      hh = fmaf(a[j], hh, e[j]);
    }
  }

  grid.sync();

  // Phase C: rescan from incoming state (dup/Av/BCsh persist)
  float Dv = Dp[d];
#pragma unroll
  for (int cc = 0; cc < 2; ++cc) {
    int c = cg * 2 + cc;
    int t0 = c * CL;
    size_t base = ((size_t)c * D_INNER + d) * NSTATE;
    float h[NSTATE];
#pragma unroll
    for (int n = 0; n < NSTATE; ++n) h[n] = hend[base + n];
#pragma unroll
    for (int tt = 0; tt < CL; ++tt) {
      unsigned p = dup[cc][tt];
      float dtv = bf2f((ushort_t)(p & 0xffffu));
      float uv  = bf2f((ushort_t)(p >> 16));
      float du = dtv * uv;
      float yv = 0.f;
#pragma unroll
      for (int n = 0; n < NSTATE; ++n) {
        float dA = exp2f(dtv * Av[n]);
        h[n] = fmaf(dA, h[n], du * BCsh[cc][tt][n]);
        yv = fmaf(h[n], BCsh[cc][tt][16 + n], yv);
      }
      float zv = bf2f(xzb[(size_t)(t0 + tt) * 4096 + D_INNER + d]);
      yb[(size_t)(t0 + tt) * D_INNER + d] = f2bf((yv + uv * Dv) * silu_f(zv));
    }
  }
}

extern "C" void kernel_launch(void* const* d_in, const int* in_sizes, int n_in,
                              void* d_out, int out_size, void* d_ws, size_t ws_size,
                              hipStream_t stream) {
  const float* h_in   = (const float*)d_in[0];
  const float* norm_w = (const float*)d_in[1];
  const float* in_w   = (const float*)d_in[2];
  const float* conv_w = (const float*)d_in[3];
  const float* conv_b = (const float*)d_in[4];
  const float* xp_w   = (const float*)d_in[5];
  const float* dt_w   = (const float*)d_in[6];
  const float* dt_b   = (const float*)d_in[7];
  const float* A_log  = (const float*)d_in[8];
  const float* Dp     = (const float*)d_in[9];
  const float* out_w  = (const float*)d_in[10];
  const float* normf  = (const float*)d_in[11];
  float* out = (float*)d_out;

  float* ws = (float*)d_ws;
  const size_t TD = (size_t)SEQ * D_MODEL;            // 2.10M
  const size_t TI = (size_t)SEQ * D_INNER;            // 4.19M
  const size_t ST = (size_t)NCH * D_INNER * NSTATE;   // 4.19M == 2*TD
  const size_t DB = (size_t)SEQ * DPROJ;
  const size_t INW = (size_t)2 * D_INNER * D_MODEL;
  const size_t XPW = (size_t)DPROJ * D_INNER;
  const size_t DTW = (size_t)D_INNER * DT_RANK;
  const size_t OUW = (size_t)D_MODEL * D_INNER;

  float* res   = ws; ws += TD;
  float* dbc   = ws; ws += DB;
  float* pk    = ws; ws += ST;   // x_proj partials / aprod / out_proj partials 0-1
  float* hend  = ws; ws += ST;   // hin after passB / out_proj partials 2-3 (pk+2TD)
  unsigned* dtu = (unsigned*)ws; ws += TI;
  ushort_t* hnb  = (ushort_t*)ws;
  ushort_t* xzb  = hnb + TD;        // 2*TI ushorts
  ushort_t* xcb  = xzb + 2 * TI;
  ushort_t* ybf  = xcb + TI;
  ushort_t* dbcb = ybf + TI;
  ushort_t* inwb = dbcb + DB;           // 2*INW (both layers)
  ushort_t* xpwb = inwb + 2 * INW;
  ushort_t* dtwb = xpwb + 2 * XPW;
  ushort_t* ouwb = dtwb + 2 * DTW;

  // convert ALL weights (both layers) in one dispatch
  {
    int n0 = (int)(2 * INW / 4), n1 = (int)(2 * XPW / 4);
    int n2 = (int)(2 * DTW / 4), n3 = (int)(2 * OUW / 4);
    int tot = n0 + n1 + n2 + n3;
    f2bf_all_kernel<<<(tot + 255) / 256, 256, 0, stream>>>(
        in_w, inwb, n0, xp_w, xpwb, n1, dt_w, dtwb, n2, out_w, ouwb, n3);
  }

  for (int i = 0; i < 2; ++i) {
    addrms_kernel<<<SEQ, 256, 0, stream>>>(
        i == 0 ? h_in : pk,
        i == 0 ? nullptr : pk + TD,
        i == 0 ? nullptr : pk + 2 * TD,
        i == 0 ? nullptr : pk + 3 * TD,
        i == 0 ? nullptr : res,
        norm_w + (size_t)i * D_MODEL, res, nullptr, hnb);
    // in_proj: [2048 x 1024] x [4096 x 1024]^T -> xzb (bf16)
    gemm_bt<1, false, 2><<<dim3(32, 16, 1), 256, 0, stream>>>(
        hnb, inwb + (size_t)i * INW, xzb, nullptr, nullptr,
        SEQ, 2 * D_INNER, D_MODEL, D_MODEL, D_MODEL, 2 * D_INNER);
    conv_silu_kernel<<<(int)(TI / 4 / 256), 256, 0, stream>>>(
        xzb, conv_w + (size_t)i * D_INNER * 4, conv_b + (size_t)i * D_INNER, xcb);
    // x_proj: split-K=16 -> pk, reduce -> dbc (f32) + dbcb (bf16)
    gemm_bt<16, true, 0><<<dim3(1, 16, 16), 256, 0, stream>>>(
        xcb, xpwb + (size_t)i * XPW, pk, nullptr, nullptr,
        SEQ, DPROJ, D_INNER, D_INNER, D_INNER, DPROJ);
    reduceN_kernel<<<(DB + 255) / 256, 256, 0, stream>>>(pk, dbc, dbcb, (int)DB, 16);
    // dt_proj -> softplus -> packed (dt | u<<16) uint buffer
    gemm_bt<1, false, 3><<<dim3(16, 16, 1), 256, 0, stream>>>(
        dbcb, dtwb + (size_t)i * DTW, dtu, dt_b + (size_t)i * D_INNER, xcb,
        SEQ, D_INNER, DT_RANK, DPROJ, DT_RANK, D_INNER);
    // fused cooperative scan; fall back to verified 3-kernel path on any error
    {
      const float* Ai = A_log + (size_t)i * D_INNER * NSTATE;
      const float* Di = Dp + (size_t)i * D_INNER;
      const unsigned* dtup = dtu;
      const ushort_t* xzp = xzb;
      float* pkp = pk; float* hep = hend; ushort_t* ybp = ybf;
      const float* dbp = dbc;
      void* args[] = { (void*)&dtup, (void*)&dbp, (void*)&Ai, (void*)&Di,
                       (void*)&xzp, (void*)&pkp, (void*)&hep, (void*)&ybp };
      hipError_t cerr = hipLaunchCooperativeKernel(
          (void*)scan_fused_kernel, dim3(512), dim3(256), args, 0, stream);
      if (cerr != hipSuccess) {
        scan_passA_kernel<<<dim3(NCH, D_INNER / 256), 256, 0, stream>>>(
            dtu, dbc, Ai, pk, hend);
        scan_passB_kernel<<<(D_INNER * NSTATE) / 64, 256, 0, stream>>>(pk, hend);
        scan_passC_kernel<<<dim3(NCH, D_INNER / 256), 256, 0, stream>>>(
            dtu, dbc, Ai, Di, xzb, hend, ybf);
      }
    }
    // out_proj: split-K=4 -> pk..pk+4*TD (pk and hend contiguous, ST==2*TD)
    gemm_bt<4, false, 0><<<dim3(8, 16, 4), 256, 0, stream>>>(
        ybf, ouwb + (size_t)i * OUW, pk, nullptr, nullptr,
        SEQ, D_MODEL, D_INNER, D_INNER, D_INNER, D_MODEL);
  }
  addrms_kernel<<<SEQ, 256, 0, stream>>>(
      pk, pk + TD, pk + 2 * TD, pk + 3 * TD, res, normf, nullptr, out, nullptr);
}

// Round 11
// 369.078 us; speedup vs baseline: 2.8110x; 2.8110x over previous
//
#include <hip/hip_runtime.h>
#include <math.h>

#define D_MODEL 1024
#define D_INNER 2048
#define DPROJ   96      // DT_RANK + 2*D_STATE
#define DT_RANK 64
#define NSTATE  16
#define SEQ     2048
#define CL      16      // chunk length for scan
#define NCH     (SEQ/CL)            // 128
#define SCAN_SEGS 4
#define SCAN_CPS  (NCH / SCAN_SEGS) // 32 chunks per segment-lane
#define LOG2E   1.44269504088896340736f

typedef unsigned short ushort_t;
typedef short v8s __attribute__((ext_vector_type(8)));
typedef unsigned short u8s __attribute__((ext_vector_type(8)));
typedef float v4f __attribute__((ext_vector_type(4)));
typedef __attribute__((address_space(3))) unsigned int as3_u32;
typedef __attribute__((address_space(1))) unsigned int as1_u32;

__device__ __forceinline__ float silu_f(float x) { return x / (1.f + expf(-x)); }

__device__ __forceinline__ ushort_t f2bf(float f) {
  union { float f; unsigned u; } x; x.f = f;
  unsigned r = x.u + 0x7fffu + ((x.u >> 16) & 1u);  // RNE; inputs finite
  return (ushort_t)(r >> 16);
}
__device__ __forceinline__ float bf2f(ushort_t b) {
  union { unsigned u; float f; } x; x.u = ((unsigned)b) << 16; return x.f;
}

// async global->LDS, 16B per lane; lds dest = wave-uniform base + lane*16
__device__ __forceinline__ void gl_lds16(const ushort_t* g, ushort_t* l) {
  __builtin_amdgcn_global_load_lds((const as1_u32*)g, (as3_u32*)l, 16, 0, 0);
}

// res = a (+a2+a3+a4) (+ b); xn = rmsnorm(res)*w -> f32 (xnf) and/or bf16 (xnb)
__global__ __launch_bounds__(256) void addrms_kernel(
    const float* __restrict__ a, const float* __restrict__ a2,
    const float* __restrict__ a3, const float* __restrict__ a4,
    const float* __restrict__ b,
    const float* __restrict__ w, float* __restrict__ res_out,
    float* __restrict__ xnf, ushort_t* __restrict__ xnb) {
  int t = blockIdx.x;
  int tid = threadIdx.x;
  float v[4];
  float ss = 0.f;
#pragma unroll
  for (int j = 0; j < 4; ++j) {
    int dcol = tid + j * 256;
    size_t off = (size_t)t * D_MODEL + dcol;
    float x = a[off];
    if (a2) x += a2[off];
    if (a3) x += a3[off];
    if (a4) x += a4[off];
    if (b) x += b[off];
    v[j] = x;
    ss += x * x;
  }
#pragma unroll
  for (int off = 32; off > 0; off >>= 1) ss += __shfl_down(ss, off);
  __shared__ float red[4];
  __shared__ float rmsv;
  int wid = tid >> 6, lane = tid & 63;
  if (lane == 0) red[wid] = ss;
  __syncthreads();
  if (tid == 0) {
    float s = red[0] + red[1] + red[2] + red[3];
    rmsv = rsqrtf(s / (float)D_MODEL + 1e-5f);
  }
  __syncthreads();
  float r = rmsv;
#pragma unroll
  for (int j = 0; j < 4; ++j) {
    int dcol = tid + j * 256;
    if (res_out) res_out[(size_t)t * D_MODEL + dcol] = v[j];
    float xn = v[j] * r * w[dcol];
    if (xnf) xnf[(size_t)t * D_MODEL + dcol] = xn;
    if (xnb) xnb[(size_t)t * D_MODEL + dcol] = f2bf(xn);
  }
}

// single-dispatch f32->bf16 of all 4 weight tensors (both layers each)
__global__ __launch_bounds__(256) void f2bf_all_kernel(
    const float* __restrict__ s0, ushort_t* __restrict__ d0, int n0,
    const float* __restrict__ s1, ushort_t* __restrict__ d1, int n1,
    const float* __restrict__ s2, ushort_t* __restrict__ d2, int n2,
    const float* __restrict__ s3, ushort_t* __restrict__ d3, int n3) {
  int j = blockIdx.x * 256 + threadIdx.x;
  const float* s; ushort_t* d;
  if (j < n0) { s = s0; d = d0; }
  else {
    j -= n0;
    if (j < n1) { s = s1; d = d1; }
    else {
      j -= n1;
      if (j < n2) { s = s2; d = d2; }
      else {
        j -= n2;
        if (j >= n3) return;
        s = s3; d = d3;
      }
    }
  }
  float4 v = ((const float4*)s)[j];
  ushort4 o;
  o.x = f2bf(v.x); o.y = f2bf(v.y); o.z = f2bf(v.z); o.w = f2bf(v.w);
  ((ushort4*)d)[j] = o;
}

// ------------- bf16 MFMA GEMM (NT): C[m,n] = sum_k A[m,k]*B[n,k] -------------
// m97 structure + double-buffered prefetch; one __syncthreads per K-step.
// EPI: 0 = f32 out, 1 = softplus(acc+bias[col]) -> bf16, 2 = bf16,
//      3 = pack( bf16(softplus(acc+bias)) | upack[idx]<<16 ) -> uint out.
template <int SPLITK, bool CLAMPN, int EPI>
__global__ __launch_bounds__(256) void gemm_bt(
    const ushort_t* __restrict__ A, const ushort_t* __restrict__ B,
    void* __restrict__ Cv, const float* __restrict__ bias,
    const ushort_t* __restrict__ upack,
    int M, int N, int K, int lda, int ldb, int ldc) {
  __shared__ ushort_t As[2][128 * 32];
  __shared__ ushort_t Bs[2][128 * 32];
  int tid = threadIdx.x;
  int bm = blockIdx.y * 128;
  int bn = blockIdx.x * 128;
  int kchunk = K / SPLITK;
  int k0 = blockIdx.z * kchunk;
  int nk = kchunk / 32;

  int lane = tid & 63, wid = tid >> 6;
  int wr = wid >> 1, wc = wid & 1;
  int lr = lane & 15;
  int ko = (lane >> 4) * 8;

  int rs0 = wid * 16 + (lane >> 2);
  int segc = (lane & 3) * 8;

  auto stage = [&](int buf, int kt) {
#pragma unroll
    for (int s = 0; s < 2; ++s) {
      int r = s * 64 + rs0;
      int cc = kt + segc;
      gl_lds16(A + (size_t)(bm + r) * lda + cc, &As[buf][s * 2048 + wid * 512]);
      int bc = bn + r;
      if (CLAMPN) bc = min(bc, N - 1);   // in-bounds; junk cols never stored
      gl_lds16(B + (size_t)bc * ldb + cc, &Bs[buf][s * 2048 + wid * 512]);
    }
  };

  v4f acc[4][4] = {};

  stage(0, k0);
  __syncthreads();
  int cur = 0;
  for (int it = 0; it < nk; ++it) {
    if (it + 1 < nk) stage(cur ^ 1, k0 + (it + 1) * 32);
    v8s a[4], b[4];
#pragma unroll
    for (int m = 0; m < 4; ++m)
      a[m] = *(const v8s*)&As[cur][(wr * 64 + m * 16 + lr) * 32 + ko];
#pragma unroll
    for (int n = 0; n < 4; ++n)
      b[n] = *(const v8s*)&Bs[cur][(wc * 64 + n * 16 + lr) * 32 + ko];
#pragma unroll
    for (int m = 0; m < 4; ++m)
#pragma unroll
      for (int n = 0; n < 4; ++n)
        acc[m][n] = __builtin_amdgcn_mfma_f32_16x16x32_bf16(a[m], b[n], acc[m][n], 0, 0, 0);
    __syncthreads();
    cur ^= 1;
  }

  float* Cf = (float*)Cv;
  ushort_t* Cb = (ushort_t*)Cv;
  unsigned* Cu = (unsigned*)Cv;
  if (SPLITK > 1) Cf += (size_t)blockIdx.z * (size_t)M * (size_t)ldc;

#pragma unroll
  for (int m = 0; m < 4; ++m) {
#pragma unroll
    for (int n = 0; n < 4; ++n) {
      int gc = bn + wc * 64 + n * 16 + lr;
      if (gc >= N) continue;
      int gr0 = bm + wr * 64 + m * 16 + (lane >> 4) * 4;
      float bv = (EPI == 1 || EPI == 3) ? bias[gc] : 0.f;
#pragma unroll
      for (int j = 0; j < 4; ++j) {
        float val = acc[m][n][j];
        size_t idx = (size_t)(gr0 + j) * ldc + gc;
        if (EPI == 0) {
          Cf[idx] = val;
        } else if (EPI == 1) {
          float x = val + bv;
          x = fmaxf(x, 0.f) + log1pf(expf(-fabsf(x)));
          Cb[idx] = f2bf(x);
        } else if (EPI == 2) {
          Cb[idx] = f2bf(val);
        } else {
          float x = val + bv;
          x = fmaxf(x, 0.f) + log1pf(expf(-fabsf(x)));
          Cu[idx] = (unsigned)f2bf(x) | ((unsigned)upack[idx] << 16);
        }
      }
    }
  }
}

// out[idx] = sum_p part[idx + p*sz]; f32 and/or bf16 outputs (nullable)
__global__ __launch_bounds__(256) void reduceN_kernel(
    const float* __restrict__ part, float* __restrict__ out,
    ushort_t* __restrict__ outb, int sz, int nparts) {
  int idx = blockIdx.x * 256 + threadIdx.x;
  if (idx >= sz) return;
  float s = 0.f;
  for (int p = 0; p < nparts; ++p) s += part[idx + (size_t)p * sz];
  if (out) out[idx] = s;
  if (outb) outb[idx] = f2bf(s);
}

// depthwise causal conv (k=4) + silu, bf16 in (xz) -> bf16 out; 4 channels/thread
__global__ __launch_bounds__(256) void conv_silu_kernel(
    const ushort_t* __restrict__ xzb, const float* __restrict__ cw,
    const float* __restrict__ cb, ushort_t* __restrict__ xcb) {
  int idx = blockIdx.x * 256 + threadIdx.x;   // over SEQ * (D_INNER/4)
  int t = idx >> 9;
  int c = (idx & 511) * 4;
  float acc[4];
  float4 cbv = *(const float4*)&cb[c];
  acc[0] = cbv.x; acc[1] = cbv.y; acc[2] = cbv.z; acc[3] = cbv.w;
  float4 wv[4];
#pragma unroll
  for (int i = 0; i < 4; ++i) wv[i] = *(const float4*)&cw[(c + i) * 4];
#pragma unroll
  for (int k = 0; k < 4; ++k) {
    int ts = t - 3 + k;
    if (ts < 0) continue;
    ushort4 x = *(const ushort4*)&xzb[(size_t)ts * 4096 + c];
    acc[0] = fmaf(bf2f(x.x), ((const float*)&wv[0])[k], acc[0]);
    acc[1] = fmaf(bf2f(x.y), ((const float*)&wv[1])[k], acc[1]);
    acc[2] = fmaf(bf2f(x.z), ((const float*)&wv[2])[k], acc[2]);
    acc[3] = fmaf(bf2f(x.w), ((const float*)&wv[3])[k], acc[3]);
  }
  ushort4 o;
  o.x = f2bf(silu_f(acc[0]));
  o.y = f2bf(silu_f(acc[1]));
  o.z = f2bf(silu_f(acc[2]));
  o.w = f2bf(silu_f(acc[3]));
  *(ushort4*)&xcb[(size_t)t * D_INNER + c] = o;
}

// Pass A: per-chunk cumulative dA product + local end state (h0 = 0).
// B rows staged to LDS from bf16 dbcb; state written as bf16 (ushort8 x2).
__global__ __launch_bounds__(256) void scan_passA_kernel(
    const unsigned* __restrict__ dtu, const ushort_t* __restrict__ dbcb,
    const float* __restrict__ A_log,
    ushort_t* __restrict__ aprodb, ushort_t* __restrict__ hendb) {
  __shared__ float Bsh[CL][16];
  int c = blockIdx.x;
  int d = blockIdx.y * 256 + threadIdx.x;
  int t0 = c * CL;
  {
    int j = threadIdx.x;           // CL*16/4 = 64 ushort4 slots
    if (j < CL * 4) {
      int r = j >> 2, col = (j & 3) * 4;
      ushort4 v = *(const ushort4*)&dbcb[(size_t)(t0 + r) * DPROJ + DT_RANK + col];
      Bsh[r][col]     = bf2f(v.x);
      Bsh[r][col + 1] = bf2f(v.y);
      Bsh[r][col + 2] = bf2f(v.z);
      Bsh[r][col + 3] = bf2f(v.w);
    }
  }
  float Av[NSTATE], h[NSTATE], ap[NSTATE];
#pragma unroll
  for (int n = 0; n < NSTATE; ++n) {
    Av[n] = -expf(A_log[(size_t)d * NSTATE + n]) * LOG2E;
    h[n] = 0.f;
    ap[n] = 1.f;
  }
  __syncthreads();
#pragma unroll 2
  for (int tt = 0; tt < CL; ++tt) {
    unsigned p = dtu[(size_t)(t0 + tt) * D_INNER + d];
    float dtv = bf2f((ushort_t)(p & 0xffffu));
    float uv  = bf2f((ushort_t)(p >> 16));
    float du = dtv * uv;
#pragma unroll
    for (int n = 0; n < NSTATE; ++n) {
      float dA = exp2f(dtv * Av[n]);
      h[n] = fmaf(dA, h[n], du * Bsh[tt][n]);
      ap[n] *= dA;
    }
  }
  size_t base = ((size_t)c * D_INNER + d) * NSTATE;
  u8s oa, ob, ha, hb;
#pragma unroll
  for (int n = 0; n < 8; ++n) {
    oa[n] = f2bf(ap[n]);     ob[n] = f2bf(ap[n + 8]);
    ha[n] = f2bf(h[n]);      hb[n] = f2bf(h[n + 8]);
  }
  *(u8s*)&aprodb[base] = oa;     *(u8s*)&aprodb[base + 8] = ob;
  *(u8s*)&hendb[base]  = ha;     *(u8s*)&hendb[base + 8]  = hb;
}

// Pass B: carry across 128 chunks (bf16 state in/out).
// Each chain (d,n): 4 lanes x 32 chunks; shfl composes segment (P,E);
// in-register rescan rewrites hendb with the INCOMING state per chunk.
__global__ __launch_bounds__(256) void scan_passB_kernel(
    const ushort_t* __restrict__ aprodb, ushort_t* __restrict__ hendb) {
  int tid = threadIdx.x;
  int lane = tid & 63;
  int wave = tid >> 6;
  int seg = lane >> 4;                       // 0..3
  int chain = blockIdx.x * 64 + wave * 16 + (lane & 15);
  const size_t stride = (size_t)D_INNER * NSTATE;
  float a[SCAN_CPS], e[SCAN_CPS];
  float P = 1.f, E = 0.f;
  int c0 = seg * SCAN_CPS;
#pragma unroll
  for (int j = 0; j < SCAN_CPS; ++j) {
    a[j] = bf2f(aprodb[(size_t)(c0 + j) * stride + chain]);
    e[j] = bf2f(hendb[(size_t)(c0 + j) * stride + chain]);
    E = fmaf(a[j], E, e[j]);
    P *= a[j];
  }
#pragma unroll
  for (int dstep = 1; dstep < SCAN_SEGS; dstep <<= 1) {
    float Pp = __shfl_up(P, dstep * 16);
    float Ep = __shfl_up(E, dstep * 16);
    if (seg >= dstep) { E = fmaf(P, Ep, E); P *= Pp; }
  }
  float Ex = __shfl_up(E, 16);
  if (seg == 0) Ex = 0.f;
  float h = Ex;
#pragma unroll
  for (int j = 0; j < SCAN_CPS; ++j) {
    hendb[(size_t)(c0 + j) * stride + chain] = f2bf(h);
    h = fmaf(a[j], h, e[j]);
  }
}

// Pass C: rescan from bf16 hin; y = (scan + u*D) * silu(z) -> bf16.
// B and C rows staged to LDS from bf16 dbcb.
__global__ __launch_bounds__(256) void scan_passC_kernel(
    const unsigned* __restrict__ dtu, const ushort_t* __restrict__ dbcb,
    const float* __restrict__ A_log, const float* __restrict__ Dp,
    const ushort_t* __restrict__ xzb, const ushort_t* __restrict__ hinb,
    ushort_t* __restrict__ yb) {
  __shared__ float BCsh[CL][32];   // [tt][0..15]=B, [16..31]=C
  int c = blockIdx.x;
  int d = blockIdx.y * 256 + threadIdx.x;
  int t0 = c * CL;
  {
    int j = threadIdx.x;           // CL*32/4 = 128 ushort4 slots
    if (j < CL * 8) {
      int r = j >> 3, col = (j & 7) * 4;
      ushort4 v = *(const ushort4*)&dbcb[(size_t)(t0 + r) * DPROJ + DT_RANK + col];
      BCsh[r][col]     = bf2f(v.x);
      BCsh[r][col + 1] = bf2f(v.y);
      BCsh[r][col + 2] = bf2f(v.z);
      BCsh[r][col + 3] = bf2f(v.w);
    }
  }
  float Av[NSTATE], h[NSTATE];
  size_t base = ((size_t)c * D_INNER + d) * NSTATE;
  u8s h0 = *(const u8s*)&hinb[base];
  u8s h1 = *(const u8s*)&hinb[base + 8];
#pragma unroll
  for (int n = 0; n < NSTATE; ++n) {
    Av[n] = -expf(A_log[(size_t)d * NSTATE + n]) * LOG2E;
    h[n] = (n < 8) ? bf2f(h0[n & 7]) : bf2f(h1[n & 7]);
  }
  float Dv = Dp[d];
  __syncthreads();
#pragma unroll 2
  for (int tt = 0; tt < CL; ++tt) {
    unsigned p = dtu[(size_t)(t0 + tt) * D_INNER + d];
    float dtv = bf2f((ushort_t)(p & 0xffffu));
    float uv  = bf2f((ushort_t)(p >> 16));
    float du = dtv * uv;
    float yv = 0.f;
#pragma unroll
    for (int n = 0; n < NSTATE; ++n) {
      float dA = exp2f(dtv * Av[n]);
      h[n] = fmaf(dA, h[n], du * BCsh[tt][n]);
      yv = fmaf(h[n], BCsh[tt][16 + n], yv);
    }
    float zv = bf2f(xzb[(size_t)(t0 + tt) * 4096 + D_INNER + d]);
    yb[(size_t)(t0 + tt) * D_INNER + d] = f2bf((yv + uv * Dv) * silu_f(zv));
  }
}

extern "C" void kernel_launch(void* const* d_in, const int* in_sizes, int n_in,
                              void* d_out, int out_size, void* d_ws, size_t ws_size,
                              hipStream_t stream) {
  const float* h_in   = (const float*)d_in[0];
  const float* norm_w = (const float*)d_in[1];
  const float* in_w   = (const float*)d_in[2];
  const float* conv_w = (const float*)d_in[3];
  const float* conv_b = (const float*)d_in[4];
  const float* xp_w   = (const float*)d_in[5];
  const float* dt_w   = (const float*)d_in[6];
  const float* dt_b   = (const float*)d_in[7];
  const float* A_log  = (const float*)d_in[8];
  const float* Dp     = (const float*)d_in[9];
  const float* out_w  = (const float*)d_in[10];
  const float* normf  = (const float*)d_in[11];
  float* out = (float*)d_out;

  float* ws = (float*)d_ws;
  const size_t TD = (size_t)SEQ * D_MODEL;            // 2.10M
  const size_t TI = (size_t)SEQ * D_INNER;            // 4.19M
  const size_t ST = (size_t)NCH * D_INNER * NSTATE;   // 4.19M elements
  const size_t DB = (size_t)SEQ * DPROJ;
  const size_t INW = (size_t)2 * D_INNER * D_MODEL;
  const size_t XPW = (size_t)DPROJ * D_INNER;
  const size_t DTW = (size_t)D_INNER * DT_RANK;
  const size_t OUW = (size_t)D_MODEL * D_INNER;

  float* res = ws; ws += TD;
  float* pk  = ws; ws += 4 * TD;    // x_proj partials (16*DB) / out_proj partials (4*TD)
  unsigned* dtu = (unsigned*)ws; ws += TI;
  ushort_t* aprodb = (ushort_t*)ws;     // ST ushorts
  ushort_t* hendb  = aprodb + ST;       // ST ushorts (hin after passB)
  ushort_t* hnb  = hendb + ST;
  ushort_t* xzb  = hnb + TD;            // 2*TI ushorts
  ushort_t* xcb  = xzb + 2 * TI;
  ushort_t* ybf  = xcb + TI;
  ushort_t* dbcb = ybf + TI;
  ushort_t* inwb = dbcb + DB;           // 2*INW (both layers)
  ushort_t* xpwb = inwb + 2 * INW;
  ushort_t* dtwb = xpwb + 2 * XPW;
  ushort_t* ouwb = dtwb + 2 * DTW;

  // convert ALL weights (both layers) in one dispatch
  {
    int n0 = (int)(2 * INW / 4), n1 = (int)(2 * XPW / 4);
    int n2 = (int)(2 * DTW / 4), n3 = (int)(2 * OUW / 4);
    int tot = n0 + n1 + n2 + n3;
    f2bf_all_kernel<<<(tot + 255) / 256, 256, 0, stream>>>(
        in_w, inwb, n0, xp_w, xpwb, n1, dt_w, dtwb, n2, out_w, ouwb, n3);
  }

  for (int i = 0; i < 2; ++i) {
    // residual update + rmsnorm; layer>0 consumes out_proj split-K=4 partials
    addrms_kernel<<<SEQ, 256, 0, stream>>>(
        i == 0 ? h_in : pk,
        i == 0 ? nullptr : pk + TD,
        i == 0 ? nullptr : pk + 2 * TD,
        i == 0 ? nullptr : pk + 3 * TD,
        i == 0 ? nullptr : res,
        norm_w + (size_t)i * D_MODEL, res, nullptr, hnb);
    // in_proj: [2048 x 1024] x [4096 x 1024]^T -> xzb (bf16)
    gemm_bt<1, false, 2><<<dim3(32, 16, 1), 256, 0, stream>>>(
        hnb, inwb + (size_t)i * INW, xzb, nullptr, nullptr,
        SEQ, 2 * D_INNER, D_MODEL, D_MODEL, D_MODEL, 2 * D_INNER);
    conv_silu_kernel<<<(int)(TI / 4 / 256), 256, 0, stream>>>(
        xzb, conv_w + (size_t)i * D_INNER * 4, conv_b + (size_t)i * D_INNER, xcb);
    // x_proj: split-K=16 -> pk (f32), reduce -> dbcb (bf16)
    gemm_bt<16, true, 0><<<dim3(1, 16, 16), 256, 0, stream>>>(
        xcb, xpwb + (size_t)i * XPW, pk, nullptr, nullptr,
        SEQ, DPROJ, D_INNER, D_INNER, D_INNER, DPROJ);
    reduceN_kernel<<<(DB + 255) / 256, 256, 0, stream>>>(
        pk, nullptr, dbcb, (int)DB, 16);
    // dt_proj -> softplus -> packed (dt | u<<16) uint buffer
    gemm_bt<1, false, 3><<<dim3(16, 16, 1), 256, 0, stream>>>(
        dbcb, dtwb + (size_t)i * DTW, dtu, dt_b + (size_t)i * D_INNER, xcb,
        SEQ, D_INNER, DT_RANK, DPROJ, DT_RANK, D_INNER);
    // scan: A -> B -> C (3 dispatches, bf16 state)
    scan_passA_kernel<<<dim3(NCH, D_INNER / 256), 256, 0, stream>>>(
        dtu, dbcb, A_log + (size_t)i * D_INNER * NSTATE, aprodb, hendb);
    scan_passB_kernel<<<(D_INNER * NSTATE) / 64, 256, 0, stream>>>(aprodb, hendb);
    scan_passC_kernel<<<dim3(NCH, D_INNER / 256), 256, 0, stream>>>(
        dtu, dbcb, A_log + (size_t)i * D_INNER * NSTATE,
        Dp + (size_t)i * D_INNER, xzb, hendb, ybf);
    // out_proj: split-K=4 -> pk..pk+4*TD partials
    gemm_bt<4, false, 0><<<dim3(8, 16, 4), 256, 0, stream>>>(
        ybf, ouwb + (size_t)i * OUW, pk, nullptr, nullptr,
        SEQ, D_MODEL, D_INNER, D_INNER, D_INNER, D_MODEL);
  }
  addrms_kernel<<<SEQ, 256, 0, stream>>>(
      pk, pk + TD, pk + 2 * TD, pk + 3 * TD, res, normf, nullptr, out, nullptr);
}

// Round 12
// 368.010 us; speedup vs baseline: 2.8191x; 1.0029x over previous
//
#include <hip/hip_runtime.h>
#include <math.h>

#define D_MODEL 1024
#define D_INNER 2048
#define DPROJ   96      // DT_RANK + 2*D_STATE
#define DT_RANK 64
#define NSTATE  16
#define SEQ     2048
#define CL      16      // chunk length for scan
#define NCH     (SEQ/CL)            // 128
#define SCAN_SEGS 4
#define SCAN_CPS  (NCH / SCAN_SEGS) // 32 chunks per segment-lane
#define LOG2E   1.44269504088896340736f

typedef unsigned short ushort_t;
typedef short v8s __attribute__((ext_vector_type(8)));
typedef unsigned short u8s __attribute__((ext_vector_type(8)));
typedef float v4f __attribute__((ext_vector_type(4)));
typedef __attribute__((address_space(3))) unsigned int as3_u32;
typedef __attribute__((address_space(1))) unsigned int as1_u32;

__device__ __forceinline__ float silu_f(float x) { return x / (1.f + expf(-x)); }

__device__ __forceinline__ ushort_t f2bf(float f) {
  union { float f; unsigned u; } x; x.f = f;
  unsigned r = x.u + 0x7fffu + ((x.u >> 16) & 1u);  // RNE; inputs finite
  return (ushort_t)(r >> 16);
}
__device__ __forceinline__ float bf2f(ushort_t b) {
  union { unsigned u; float f; } x; x.u = ((unsigned)b) << 16; return x.f;
}

// async global->LDS, 16B per lane; lds dest = wave-uniform base + lane*16
__device__ __forceinline__ void gl_lds16(const ushort_t* g, ushort_t* l) {
  __builtin_amdgcn_global_load_lds((const as1_u32*)g, (as3_u32*)l, 16, 0, 0);
}

// res = a (+a2+a3+a4) (+ b); xn = rmsnorm(res)*w -> f32 (xnf) and/or bf16 (xnb)
__global__ __launch_bounds__(256) void addrms_kernel(
    const float* __restrict__ a, const float* __restrict__ a2,
    const float* __restrict__ a3, const float* __restrict__ a4,
    const float* __restrict__ b,
    const float* __restrict__ w, float* __restrict__ res_out,
    float* __restrict__ xnf, ushort_t* __restrict__ xnb) {
  int t = blockIdx.x;
  int tid = threadIdx.x;
  float v[4];
  float ss = 0.f;
#pragma unroll
  for (int j = 0; j < 4; ++j) {
    int dcol = tid + j * 256;
    size_t off = (size_t)t * D_MODEL + dcol;
    float x = a[off];
    if (a2) x += a2[off];
    if (a3) x += a3[off];
    if (a4) x += a4[off];
    if (b) x += b[off];
    v[j] = x;
    ss += x * x;
  }
#pragma unroll
  for (int off = 32; off > 0; off >>= 1) ss += __shfl_down(ss, off);
  __shared__ float red[4];
  __shared__ float rmsv;
  int wid = tid >> 6, lane = tid & 63;
  if (lane == 0) red[wid] = ss;
  __syncthreads();
  if (tid == 0) {
    float s = red[0] + red[1] + red[2] + red[3];
    rmsv = rsqrtf(s / (float)D_MODEL + 1e-5f);
  }
  __syncthreads();
  float r = rmsv;
#pragma unroll
  for (int j = 0; j < 4; ++j) {
    int dcol = tid + j * 256;
    if (res_out) res_out[(size_t)t * D_MODEL + dcol] = v[j];
    float xn = v[j] * r * w[dcol];
    if (xnf) xnf[(size_t)t * D_MODEL + dcol] = xn;
    if (xnb) xnb[(size_t)t * D_MODEL + dcol] = f2bf(xn);
  }
}

// single-dispatch f32->bf16 of all 4 weight tensors (both layers each)
__global__ __launch_bounds__(256) void f2bf_all_kernel(
    const float* __restrict__ s0, ushort_t* __restrict__ d0, int n0,
    const float* __restrict__ s1, ushort_t* __restrict__ d1, int n1,
    const float* __restrict__ s2, ushort_t* __restrict__ d2, int n2,
    const float* __restrict__ s3, ushort_t* __restrict__ d3, int n3) {
  int j = blockIdx.x * 256 + threadIdx.x;
  const float* s; ushort_t* d;
  if (j < n0) { s = s0; d = d0; }
  else {
    j -= n0;
    if (j < n1) { s = s1; d = d1; }
    else {
      j -= n1;
      if (j < n2) { s = s2; d = d2; }
      else {
        j -= n2;
        if (j >= n3) return;
        s = s3; d = d3;
      }
    }
  }
  float4 v = ((const float4*)s)[j];
  ushort4 o;
  o.x = f2bf(v.x); o.y = f2bf(v.y); o.z = f2bf(v.z); o.w = f2bf(v.w);
  ((ushort4*)d)[j] = o;
}

// ------------- bf16 MFMA GEMM (NT): C[m,n] = sum_k A[m,k]*B[n,k] -------------
// m97 structure + double-buffered prefetch; one __syncthreads per K-step.
// XCD-aware bijective block swizzle (m204): each XCD owns a contiguous chunk
// of the x-major logical grid -> A-panel stays resident in one XCD's L2.
// EPI: 0 = f32 out, 1 = softplus(acc+bias[col]) -> bf16, 2 = bf16,
//      3 = pack( bf16(softplus(acc+bias)) | upack[idx]<<16 ) -> uint out.
template <int SPLITK, bool CLAMPN, int EPI>
__global__ __launch_bounds__(256) void gemm_bt(
    const ushort_t* __restrict__ A, const ushort_t* __restrict__ B,
    void* __restrict__ Cv, const float* __restrict__ bias,
    const ushort_t* __restrict__ upack,
    int M, int N, int K, int lda, int ldb, int ldc) {
  __shared__ ushort_t As[2][128 * 32];
  __shared__ ushort_t Bs[2][128 * 32];
  int tid = threadIdx.x;

  // bijective XCD swizzle of the flattened block id
  int gx = gridDim.x, gy = gridDim.y;
  int nwg = gx * gy * gridDim.z;
  int phys = blockIdx.x + gx * (blockIdx.y + gy * blockIdx.z);
  int q = nwg >> 3, r = nwg & 7;
  int xcd = phys & 7, idx8 = phys >> 3;
  int lbid = (xcd < r ? xcd * (q + 1) : r * (q + 1) + (xcd - r) * q) + idx8;
  int bx = lbid % gx, by = (lbid / gx) % gy, bz = lbid / (gx * gy);

  int bm = by * 128;
  int bn = bx * 128;
  int kchunk = K / SPLITK;
  int k0 = bz * kchunk;
  int nk = kchunk / 32;

  int lane = tid & 63, wid = tid >> 6;
  int wr = wid >> 1, wc = wid & 1;
  int lr = lane & 15;
  int ko = (lane >> 4) * 8;

  int rs0 = wid * 16 + (lane >> 2);
  int segc = (lane & 3) * 8;

  auto stage = [&](int buf, int kt) {
#pragma unroll
    for (int s = 0; s < 2; ++s) {
      int r2 = s * 64 + rs0;
      int cc = kt + segc;
      gl_lds16(A + (size_t)(bm + r2) * lda + cc, &As[buf][s * 2048 + wid * 512]);
      int bc = bn + r2;
      if (CLAMPN) bc = min(bc, N - 1);   // in-bounds; junk cols never stored
      gl_lds16(B + (size_t)bc * ldb + cc, &Bs[buf][s * 2048 + wid * 512]);
    }
  };

  v4f acc[4][4] = {};

  stage(0, k0);
  __syncthreads();
  int cur = 0;
  for (int it = 0; it < nk; ++it) {
    if (it + 1 < nk) stage(cur ^ 1, k0 + (it + 1) * 32);
    v8s a[4], b[4];
#pragma unroll
    for (int m = 0; m < 4; ++m)
      a[m] = *(const v8s*)&As[cur][(wr * 64 + m * 16 + lr) * 32 + ko];
#pragma unroll
    for (int n = 0; n < 4; ++n)
      b[n] = *(const v8s*)&Bs[cur][(wc * 64 + n * 16 + lr) * 32 + ko];
#pragma unroll
    for (int m = 0; m < 4; ++m)
#pragma unroll
      for (int n = 0; n < 4; ++n)
        acc[m][n] = __builtin_amdgcn_mfma_f32_16x16x32_bf16(a[m], b[n], acc[m][n], 0, 0, 0);
    __syncthreads();
    cur ^= 1;
  }

  float* Cf = (float*)Cv;
  ushort_t* Cb = (ushort_t*)Cv;
  unsigned* Cu = (unsigned*)Cv;
  if (SPLITK > 1) Cf += (size_t)bz * (size_t)M * (size_t)ldc;

#pragma unroll
  for (int m = 0; m < 4; ++m) {
#pragma unroll
    for (int n = 0; n < 4; ++n) {
      int gc = bn + wc * 64 + n * 16 + lr;
      if (gc >= N) continue;
      int gr0 = bm + wr * 64 + m * 16 + (lane >> 4) * 4;
      float bv = (EPI == 1 || EPI == 3) ? bias[gc] : 0.f;
#pragma unroll
      for (int j = 0; j < 4; ++j) {
        float val = acc[m][n][j];
        size_t idx = (size_t)(gr0 + j) * ldc + gc;
        if (EPI == 0) {
          Cf[idx] = val;
        } else if (EPI == 1) {
          float x = val + bv;
          x = fmaxf(x, 0.f) + log1pf(expf(-fabsf(x)));
          Cb[idx] = f2bf(x);
        } else if (EPI == 2) {
          Cb[idx] = f2bf(val);
        } else {
          float x = val + bv;
          x = fmaxf(x, 0.f) + log1pf(expf(-fabsf(x)));
          Cu[idx] = (unsigned)f2bf(x) | ((unsigned)upack[idx] << 16);
        }
      }
    }
  }
}

// out[idx] = sum_p part[idx + p*sz]; f32 and/or bf16 outputs (nullable)
__global__ __launch_bounds__(256) void reduceN_kernel(
    const float* __restrict__ part, float* __restrict__ out,
    ushort_t* __restrict__ outb, int sz, int nparts) {
  int idx = blockIdx.x * 256 + threadIdx.x;
  if (idx >= sz) return;
  float s = 0.f;
  for (int p = 0; p < nparts; ++p) s += part[idx + (size_t)p * sz];
  if (out) out[idx] = s;
  if (outb) outb[idx] = f2bf(s);
}

// depthwise causal conv (k=4) + silu, bf16 in (xz) -> bf16 out; 4 channels/thread
__global__ __launch_bounds__(256) void conv_silu_kernel(
    const ushort_t* __restrict__ xzb, const float* __restrict__ cw,
    const float* __restrict__ cb, ushort_t* __restrict__ xcb) {
  int idx = blockIdx.x * 256 + threadIdx.x;   // over SEQ * (D_INNER/4)
  int t = idx >> 9;
  int c = (idx & 511) * 4;
  float acc[4];
  float4 cbv = *(const float4*)&cb[c];
  acc[0] = cbv.x; acc[1] = cbv.y; acc[2] = cbv.z; acc[3] = cbv.w;
  float4 wv[4];
#pragma unroll
  for (int i = 0; i < 4; ++i) wv[i] = *(const float4*)&cw[(c + i) * 4];
#pragma unroll
  for (int k = 0; k < 4; ++k) {
    int ts = t - 3 + k;
    if (ts < 0) continue;
    ushort4 x = *(const ushort4*)&xzb[(size_t)ts * 4096 + c];
    acc[0] = fmaf(bf2f(x.x), ((const float*)&wv[0])[k], acc[0]);
    acc[1] = fmaf(bf2f(x.y), ((const float*)&wv[1])[k], acc[1]);
    acc[2] = fmaf(bf2f(x.z), ((const float*)&wv[2])[k], acc[2]);
    acc[3] = fmaf(bf2f(x.w), ((const float*)&wv[3])[k], acc[3]);
  }
  ushort4 o;
  o.x = f2bf(silu_f(acc[0]));
  o.y = f2bf(silu_f(acc[1]));
  o.z = f2bf(silu_f(acc[2]));
  o.w = f2bf(silu_f(acc[3]));
  *(ushort4*)&xcb[(size_t)t * D_INNER + c] = o;
}

// Pass A: per-chunk cumulative dA product + local end state (h0 = 0).
__global__ __launch_bounds__(256) void scan_passA_kernel(
    const unsigned* __restrict__ dtu, const ushort_t* __restrict__ dbcb,
    const float* __restrict__ A_log,
    ushort_t* __restrict__ aprodb, ushort_t* __restrict__ hendb) {
  __shared__ float Bsh[CL][16];
  int c = blockIdx.x;
  int d = blockIdx.y * 256 + threadIdx.x;
  int t0 = c * CL;
  {
    int j = threadIdx.x;           // CL*16/4 = 64 ushort4 slots
    if (j < CL * 4) {
      int r = j >> 2, col = (j & 3) * 4;
      ushort4 v = *(const ushort4*)&dbcb[(size_t)(t0 + r) * DPROJ + DT_RANK + col];
      Bsh[r][col]     = bf2f(v.x);
      Bsh[r][col + 1] = bf2f(v.y);
      Bsh[r][col + 2] = bf2f(v.z);
      Bsh[r][col + 3] = bf2f(v.w);
    }
  }
  float Av[NSTATE], h[NSTATE], ap[NSTATE];
#pragma unroll
  for (int n = 0; n < NSTATE; ++n) {
    Av[n] = -expf(A_log[(size_t)d * NSTATE + n]) * LOG2E;
    h[n] = 0.f;
    ap[n] = 1.f;
  }
  __syncthreads();
#pragma unroll 2
  for (int tt = 0; tt < CL; ++tt) {
    unsigned p = dtu[(size_t)(t0 + tt) * D_INNER + d];
    float dtv = bf2f((ushort_t)(p & 0xffffu));
    float uv  = bf2f((ushort_t)(p >> 16));
    float du = dtv * uv;
#pragma unroll
    for (int n = 0; n < NSTATE; ++n) {
      float dA = exp2f(dtv * Av[n]);
      h[n] = fmaf(dA, h[n], du * Bsh[tt][n]);
      ap[n] *= dA;
    }
  }
  size_t base = ((size_t)c * D_INNER + d) * NSTATE;
  u8s oa, ob, ha, hb;
#pragma unroll
  for (int n = 0; n < 8; ++n) {
    oa[n] = f2bf(ap[n]);     ob[n] = f2bf(ap[n + 8]);
    ha[n] = f2bf(h[n]);      hb[n] = f2bf(h[n + 8]);
  }
  *(u8s*)&aprodb[base] = oa;     *(u8s*)&aprodb[base + 8] = ob;
  *(u8s*)&hendb[base]  = ha;     *(u8s*)&hendb[base + 8]  = hb;
}

// Pass B: carry across 128 chunks (bf16 state in/out).
__global__ __launch_bounds__(256) void scan_passB_kernel(
    const ushort_t* __restrict__ aprodb, ushort_t* __restrict__ hendb) {
  int tid = threadIdx.x;
  int lane = tid & 63;
  int wave = tid >> 6;
  int seg = lane >> 4;                       // 0..3
  int chain = blockIdx.x * 64 + wave * 16 + (lane & 15);
  const size_t stride = (size_t)D_INNER * NSTATE;
  float a[SCAN_CPS], e[SCAN_CPS];
  float P = 1.f, E = 0.f;
  int c0 = seg * SCAN_CPS;
#pragma unroll
  for (int j = 0; j < SCAN_CPS; ++j) {
    a[j] = bf2f(aprodb[(size_t)(c0 + j) * stride + chain]);
    e[j] = bf2f(hendb[(size_t)(c0 + j) * stride + chain]);
    E = fmaf(a[j], E, e[j]);
    P *= a[j];
  }
#pragma unroll
  for (int dstep = 1; dstep < SCAN_SEGS; dstep <<= 1) {
    float Pp = __shfl_up(P, dstep * 16);
    float Ep = __shfl_up(E, dstep * 16);
    if (seg >= dstep) { E = fmaf(P, Ep, E); P *= Pp; }
  }
  float Ex = __shfl_up(E, 16);
  if (seg == 0) Ex = 0.f;
  float h = Ex;
#pragma unroll
  for (int j = 0; j < SCAN_CPS; ++j) {
    hendb[(size_t)(c0 + j) * stride + chain] = f2bf(h);
    h = fmaf(a[j], h, e[j]);
  }
}

// Pass C: rescan from bf16 hin; y = (scan + u*D) * silu(z) -> bf16.
__global__ __launch_bounds__(256) void scan_passC_kernel(
    const unsigned* __restrict__ dtu, const ushort_t* __restrict__ dbcb,
    const float* __restrict__ A_log, const float* __restrict__ Dp,
    const ushort_t* __restrict__ xzb, const ushort_t* __restrict__ hinb,
    ushort_t* __restrict__ yb) {
  __shared__ float BCsh[CL][32];   // [tt][0..15]=B, [16..31]=C
  int c = blockIdx.x;
  int d = blockIdx.y * 256 + threadIdx.x;
  int t0 = c * CL;
  {
    int j = threadIdx.x;           // CL*32/4 = 128 ushort4 slots
    if (j < CL * 8) {
      int r = j >> 3, col = (j & 7) * 4;
      ushort4 v = *(const ushort4*)&dbcb[(size_t)(t0 + r) * DPROJ + DT_RANK + col];
      BCsh[r][col]     = bf2f(v.x);
      BCsh[r][col + 1] = bf2f(v.y);
      BCsh[r][col + 2] = bf2f(v.z);
      BCsh[r][col + 3] = bf2f(v.w);
    }
  }
  float Av[NSTATE], h[NSTATE];
  size_t base = ((size_t)c * D_INNER + d) * NSTATE;
  u8s h0 = *(const u8s*)&hinb[base];
  u8s h1 = *(const u8s*)&hinb[base + 8];
#pragma unroll
  for (int n = 0; n < NSTATE; ++n) {
    Av[n] = -expf(A_log[(size_t)d * NSTATE + n]) * LOG2E;
    h[n] = (n < 8) ? bf2f(h0[n & 7]) : bf2f(h1[n & 7]);
  }
  float Dv = Dp[d];
  __syncthreads();
#pragma unroll 2
  for (int tt = 0; tt < CL; ++tt) {
    unsigned p = dtu[(size_t)(t0 + tt) * D_INNER + d];
    float dtv = bf2f((ushort_t)(p & 0xffffu));
    float uv  = bf2f((ushort_t)(p >> 16));
    float du = dtv * uv;
    float yv = 0.f;
#pragma unroll
    for (int n = 0; n < NSTATE; ++n) {
      float dA = exp2f(dtv * Av[n]);
      h[n] = fmaf(dA, h[n], du * BCsh[tt][n]);
      yv = fmaf(h[n], BCsh[tt][16 + n], yv);
    }
    float zv = bf2f(xzb[(size_t)(t0 + tt) * 4096 + D_INNER + d]);
    yb[(size_t)(t0 + tt) * D_INNER + d] = f2bf((yv + uv * Dv) * silu_f(zv));
  }
}

extern "C" void kernel_launch(void* const* d_in, const int* in_sizes, int n_in,
                              void* d_out, int out_size, void* d_ws, size_t ws_size,
                              hipStream_t stream) {
  const float* h_in   = (const float*)d_in[0];
  const float* norm_w = (const float*)d_in[1];
  const float* in_w   = (const float*)d_in[2];
  const float* conv_w = (const float*)d_in[3];
  const float* conv_b = (const float*)d_in[4];
  const float* xp_w   = (const float*)d_in[5];
  const float* dt_w   = (const float*)d_in[6];
  const float* dt_b   = (const float*)d_in[7];
  const float* A_log  = (const float*)d_in[8];
  const float* Dp     = (const float*)d_in[9];
  const float* out_w  = (const float*)d_in[10];
  const float* normf  = (const float*)d_in[11];
  float* out = (float*)d_out;

  float* ws = (float*)d_ws;
  const size_t TD = (size_t)SEQ * D_MODEL;            // 2.10M
  const size_t TI = (size_t)SEQ * D_INNER;            // 4.19M
  const size_t ST = (size_t)NCH * D_INNER * NSTATE;   // 4.19M elements
  const size_t DB = (size_t)SEQ * DPROJ;
  const size_t INW = (size_t)2 * D_INNER * D_MODEL;
  const size_t XPW = (size_t)DPROJ * D_INNER;
  const size_t DTW = (size_t)D_INNER * DT_RANK;
  const size_t OUW = (size_t)D_MODEL * D_INNER;

  float* res = ws; ws += TD;
  float* pk  = ws; ws += 4 * TD;    // x_proj partials (16*DB) / out_proj partials (4*TD)
  unsigned* dtu = (unsigned*)ws; ws += TI;
  ushort_t* aprodb = (ushort_t*)ws;     // ST ushorts
  ushort_t* hendb  = aprodb + ST;       // ST ushorts (hin after passB)
  ushort_t* hnb  = hendb + ST;
  ushort_t* xzb  = hnb + TD;            // 2*TI ushorts
  ushort_t* xcb  = xzb + 2 * TI;
  ushort_t* ybf  = xcb + TI;
  ushort_t* dbcb = ybf + TI;
  ushort_t* inwb = dbcb + DB;           // 2*INW (both layers)
  ushort_t* xpwb = inwb + 2 * INW;
  ushort_t* dtwb = xpwb + 2 * XPW;
  ushort_t* ouwb = dtwb + 2 * DTW;

  // convert ALL weights (both layers) in one dispatch
  {
    int n0 = (int)(2 * INW / 4), n1 = (int)(2 * XPW / 4);
    int n2 = (int)(2 * DTW / 4), n3 = (int)(2 * OUW / 4);
    int tot = n0 + n1 + n2 + n3;
    f2bf_all_kernel<<<(tot + 255) / 256, 256, 0, stream>>>(
        in_w, inwb, n0, xp_w, xpwb, n1, dt_w, dtwb, n2, out_w, ouwb, n3);
  }

  for (int i = 0; i < 2; ++i) {
    // residual update + rmsnorm; layer>0 consumes out_proj split-K=4 partials
    addrms_kernel<<<SEQ, 256, 0, stream>>>(
        i == 0 ? h_in : pk,
        i == 0 ? nullptr : pk + TD,
        i == 0 ? nullptr : pk + 2 * TD,
        i == 0 ? nullptr : pk + 3 * TD,
        i == 0 ? nullptr : res,
        norm_w + (size_t)i * D_MODEL, res, nullptr, hnb);
    // in_proj: [2048 x 1024] x [4096 x 1024]^T -> xzb (bf16)
    gemm_bt<1, false, 2><<<dim3(32, 16, 1), 256, 0, stream>>>(
        hnb, inwb + (size_t)i * INW, xzb, nullptr, nullptr,
        SEQ, 2 * D_INNER, D_MODEL, D_MODEL, D_MODEL, 2 * D_INNER);
    conv_silu_kernel<<<(int)(TI / 4 / 256), 256, 0, stream>>>(
        xzb, conv_w + (size_t)i * D_INNER * 4, conv_b + (size_t)i * D_INNER, xcb);
    // x_proj: split-K=16 -> pk (f32), reduce -> dbcb (bf16)
    gemm_bt<16, true, 0><<<dim3(1, 16, 16), 256, 0, stream>>>(
        xcb, xpwb + (size_t)i * XPW, pk, nullptr, nullptr,
        SEQ, DPROJ, D_INNER, D_INNER, D_INNER, DPROJ);
    reduceN_kernel<<<(DB + 255) / 256, 256, 0, stream>>>(
        pk, nullptr, dbcb, (int)DB, 16);
    // dt_proj -> softplus -> packed (dt | u<<16) uint buffer
    gemm_bt<1, false, 3><<<dim3(16, 16, 1), 256, 0, stream>>>(
        dbcb, dtwb + (size_t)i * DTW, dtu, dt_b + (size_t)i * D_INNER, xcb,
        SEQ, D_INNER, DT_RANK, DPROJ, DT_RANK, D_INNER);
    // scan: A -> B -> C (3 dispatches, bf16 state)
    scan_passA_kernel<<<dim3(NCH, D_INNER / 256), 256, 0, stream>>>(
        dtu, dbcb, A_log + (size_t)i * D_INNER * NSTATE, aprodb, hendb);
    scan_passB_kernel<<<(D_INNER * NSTATE) / 64, 256, 0, stream>>>(aprodb, hendb);
    scan_passC_kernel<<<dim3(NCH, D_INNER / 256), 256, 0, stream>>>(
        dtu, dbcb, A_log + (size_t)i * D_INNER * NSTATE,
        Dp + (size_t)i * D_INNER, xzb, hendb, ybf);
    // out_proj: split-K=4 -> pk..pk+4*TD partials
    gemm_bt<4, false, 0><<<dim3(8, 16, 4), 256, 0, stream>>>(
        ybf, ouwb + (size_t)i * OUW, pk, nullptr, nullptr,
        SEQ, D_MODEL, D_INNER, D_INNER, D_INNER, D_MODEL);
  }
  addrms_kernel<<<SEQ, 256, 0, stream>>>(
      pk, pk + TD, pk + 2 * TD, pk + 3 * TD, res, normf, nullptr, out, nullptr);
}

// Round 13
// 349.063 us; speedup vs baseline: 2.9721x; 1.0543x over previous
//
#include <hip/hip_runtime.h>
#include <math.h>

#define D_MODEL 1024
#define D_INNER 2048
#define DPROJ   96      // DT_RANK + 2*D_STATE
#define DT_RANK 64
#define NSTATE  16
#define SEQ     2048
#define CL      16      // chunk length for scan
#define NCH     (SEQ/CL)            // 128
#define SCAN_SEGS 4
#define SCAN_CPS  (NCH / SCAN_SEGS) // 32 chunks per segment-lane
#define LOG2E   1.44269504088896340736f
#define TDC     ((size_t)SEQ * D_MODEL)   // compile-time TD for addrms p4 stride

typedef unsigned short ushort_t;
typedef short v8s __attribute__((ext_vector_type(8)));
typedef unsigned short u8s __attribute__((ext_vector_type(8)));
typedef float v4f __attribute__((ext_vector_type(4)));
typedef __attribute__((address_space(3))) unsigned int as3_u32;
typedef __attribute__((address_space(1))) unsigned int as1_u32;

__device__ __forceinline__ float silu_f(float x) { return x / (1.f + expf(-x)); }

__device__ __forceinline__ ushort_t f2bf(float f) {
  union { float f; unsigned u; } x; x.f = f;
  unsigned r = x.u + 0x7fffu + ((x.u >> 16) & 1u);  // RNE; inputs finite
  return (ushort_t)(r >> 16);
}
__device__ __forceinline__ float bf2f(ushort_t b) {
  union { unsigned u; float f; } x; x.u = ((unsigned)b) << 16; return x.f;
}

// async global->LDS, 16B per lane; lds dest = wave-uniform base + lane*16
__device__ __forceinline__ void gl_lds16(const ushort_t* g, ushort_t* l) {
  __builtin_amdgcn_global_load_lds((const as1_u32*)g, (as3_u32*)l, 16, 0, 0);
}

// x = (p4 ? sum of 4 bf16 partials : a) (+ b); res_out = x;
// xn = rmsnorm(x)*w -> f32 (xnf) and/or bf16 (xnb)
__global__ __launch_bounds__(256) void addrms_kernel(
    const float* __restrict__ a, const ushort_t* __restrict__ p4,
    const float* __restrict__ b,
    const float* __restrict__ w, float* __restrict__ res_out,
    float* __restrict__ xnf, ushort_t* __restrict__ xnb) {
  int t = blockIdx.x;
  int tid = threadIdx.x;
  float v[4];
  float ss = 0.f;
#pragma unroll
  for (int j = 0; j < 4; ++j) {
    int dcol = tid + j * 256;
    size_t off = (size_t)t * D_MODEL + dcol;
    float x;
    if (p4) {
      x = bf2f(p4[off]) + bf2f(p4[off + TDC]) +
          bf2f(p4[off + 2 * TDC]) + bf2f(p4[off + 3 * TDC]);
    } else {
      x = a[off];
    }
    if (b) x += b[off];
    v[j] = x;
    ss += x * x;
  }
#pragma unroll
  for (int off = 32; off > 0; off >>= 1) ss += __shfl_down(ss, off);
  __shared__ float red[4];
  __shared__ float rmsv;
  int wid = tid >> 6, lane = tid & 63;
  if (lane == 0) red[wid] = ss;
  __syncthreads();
  if (tid == 0) {
    float s = red[0] + red[1] + red[2] + red[3];
    rmsv = rsqrtf(s / (float)D_MODEL + 1e-5f);
  }
  __syncthreads();
  float r = rmsv;
#pragma unroll
  for (int j = 0; j < 4; ++j) {
    int dcol = tid + j * 256;
    if (res_out) res_out[(size_t)t * D_MODEL + dcol] = v[j];
    float xn = v[j] * r * w[dcol];
    if (xnf) xnf[(size_t)t * D_MODEL + dcol] = xn;
    if (xnb) xnb[(size_t)t * D_MODEL + dcol] = f2bf(xn);
  }
}

// single-dispatch f32->bf16 of all 4 weight tensors (both layers each)
__global__ __launch_bounds__(256) void f2bf_all_kernel(
    const float* __restrict__ s0, ushort_t* __restrict__ d0, int n0,
    const float* __restrict__ s1, ushort_t* __restrict__ d1, int n1,
    const float* __restrict__ s2, ushort_t* __restrict__ d2, int n2,
    const float* __restrict__ s3, ushort_t* __restrict__ d3, int n3) {
  int j = blockIdx.x * 256 + threadIdx.x;
  const float* s; ushort_t* d;
  if (j < n0) { s = s0; d = d0; }
  else {
    j -= n0;
    if (j < n1) { s = s1; d = d1; }
    else {
      j -= n1;
      if (j < n2) { s = s2; d = d2; }
      else {
        j -= n2;
        if (j >= n3) return;
        s = s3; d = d3;
      }
    }
  }
  float4 v = ((const float4*)s)[j];
  ushort4 o;
  o.x = f2bf(v.x); o.y = f2bf(v.y); o.z = f2bf(v.z); o.w = f2bf(v.w);
  ((ushort4*)d)[j] = o;
}

// ------------- bf16 MFMA GEMM (NT): C[m,n] = sum_k A[m,k]*B[n,k] -------------
// m97 structure + double-buffered prefetch; one __syncthreads per K-step.
// XCD-aware bijective block swizzle (m204). SPLITK>1: partials at z*M*ldc.
// EPI: 0 = f32 out, 1 = softplus(acc+bias[col]) -> bf16, 2 = bf16,
//      3 = pack( bf16(softplus(acc+bias)) | upack[idx]<<16 ) -> uint out.
template <int SPLITK, bool CLAMPN, int EPI>
__global__ __launch_bounds__(256) void gemm_bt(
    const ushort_t* __restrict__ A, const ushort_t* __restrict__ B,
    void* __restrict__ Cv, const float* __restrict__ bias,
    const ushort_t* __restrict__ upack,
    int M, int N, int K, int lda, int ldb, int ldc) {
  __shared__ ushort_t As[2][128 * 32];
  __shared__ ushort_t Bs[2][128 * 32];
  int tid = threadIdx.x;

  // bijective XCD swizzle of the flattened block id
  int gx = gridDim.x, gy = gridDim.y;
  int nwg = gx * gy * gridDim.z;
  int phys = blockIdx.x + gx * (blockIdx.y + gy * blockIdx.z);
  int q = nwg >> 3, r = nwg & 7;
  int xcd = phys & 7, idx8 = phys >> 3;
  int lbid = (xcd < r ? xcd * (q + 1) : r * (q + 1) + (xcd - r) * q) + idx8;
  int bx = lbid % gx, by = (lbid / gx) % gy, bz = lbid / (gx * gy);

  int bm = by * 128;
  int bn = bx * 128;
  int kchunk = K / SPLITK;
  int k0 = bz * kchunk;
  int nk = kchunk / 32;

  int lane = tid & 63, wid = tid >> 6;
  int wr = wid >> 1, wc = wid & 1;
  int lr = lane & 15;
  int ko = (lane >> 4) * 8;

  int rs0 = wid * 16 + (lane >> 2);
  int segc = (lane & 3) * 8;

  auto stage = [&](int buf, int kt) {
#pragma unroll
    for (int s = 0; s < 2; ++s) {
      int r2 = s * 64 + rs0;
      int cc = kt + segc;
      gl_lds16(A + (size_t)(bm + r2) * lda + cc, &As[buf][s * 2048 + wid * 512]);
      int bc = bn + r2;
      if (CLAMPN) bc = min(bc, N - 1);   // in-bounds; junk cols never stored
      gl_lds16(B + (size_t)bc * ldb + cc, &Bs[buf][s * 2048 + wid * 512]);
    }
  };

  v4f acc[4][4] = {};

  stage(0, k0);
  __syncthreads();
  int cur = 0;
  for (int it = 0; it < nk; ++it) {
    if (it + 1 < nk) stage(cur ^ 1, k0 + (it + 1) * 32);
    v8s a[4], b[4];
#pragma unroll
    for (int m = 0; m < 4; ++m)
      a[m] = *(const v8s*)&As[cur][(wr * 64 + m * 16 + lr) * 32 + ko];
#pragma unroll
    for (int n = 0; n < 4; ++n)
      b[n] = *(const v8s*)&Bs[cur][(wc * 64 + n * 16 + lr) * 32 + ko];
#pragma unroll
    for (int m = 0; m < 4; ++m)
#pragma unroll
      for (int n = 0; n < 4; ++n)
        acc[m][n] = __builtin_amdgcn_mfma_f32_16x16x32_bf16(a[m], b[n], acc[m][n], 0, 0, 0);
    __syncthreads();
    cur ^= 1;
  }

  float* Cf = (float*)Cv;
  ushort_t* Cb = (ushort_t*)Cv;
  unsigned* Cu = (unsigned*)Cv;
  size_t zoff = (SPLITK > 1) ? (size_t)bz * (size_t)M * (size_t)ldc : 0;

#pragma unroll
  for (int m = 0; m < 4; ++m) {
#pragma unroll
    for (int n = 0; n < 4; ++n) {
      int gc = bn + wc * 64 + n * 16 + lr;
      if (gc >= N) continue;
      int gr0 = bm + wr * 64 + m * 16 + (lane >> 4) * 4;
      float bv = (EPI == 1 || EPI == 3) ? bias[gc] : 0.f;
#pragma unroll
      for (int j = 0; j < 4; ++j) {
        float val = acc[m][n][j];
        size_t idx = zoff + (size_t)(gr0 + j) * ldc + gc;
        if (EPI == 0) {
          Cf[idx] = val;
        } else if (EPI == 1) {
          float x = val + bv;
          x = fmaxf(x, 0.f) + log1pf(expf(-fabsf(x)));
          Cb[idx] = f2bf(x);
        } else if (EPI == 2) {
          Cb[idx] = f2bf(val);
        } else {
          float x = val + bv;
          x = fmaxf(x, 0.f) + log1pf(expf(-fabsf(x)));
          Cu[idx] = (unsigned)f2bf(x) | ((unsigned)upack[idx] << 16);
        }
      }
    }
  }
}

// outb[idx] = bf16( sum_p bf2f(part[idx + p*sz]) )
__global__ __launch_bounds__(256) void reduceNb_kernel(
    const ushort_t* __restrict__ part, ushort_t* __restrict__ outb,
    int sz, int nparts) {
  int idx = blockIdx.x * 256 + threadIdx.x;
  if (idx >= sz) return;
  float s = 0.f;
  for (int p = 0; p < nparts; ++p) s += bf2f(part[idx + (size_t)p * sz]);
  outb[idx] = f2bf(s);
}

// depthwise causal conv (k=4) + silu, bf16 -> bf16; 4 channels x 4 t-steps/thread
__global__ __launch_bounds__(256) void conv_silu_kernel(
    const ushort_t* __restrict__ xzb, const float* __restrict__ cw,
    const float* __restrict__ cb, ushort_t* __restrict__ xcb) {
  int idx = blockIdx.x * 256 + threadIdx.x;   // over (SEQ/4) * (D_INNER/4)
  int tq = idx >> 9;                // 0..511
  int c = (idx & 511) * 4;
  int t0 = tq * 4;
  float4 cbv = *(const float4*)&cb[c];
  float4 wv[4];
#pragma unroll
  for (int i = 0; i < 4; ++i) wv[i] = *(const float4*)&cw[(c + i) * 4];
  float rows[7][4];
#pragma unroll
  for (int k = 0; k < 7; ++k) {
    int ts = t0 - 3 + k;
    if (ts < 0) {
      rows[k][0] = rows[k][1] = rows[k][2] = rows[k][3] = 0.f;
    } else {
      ushort4 x = *(const ushort4*)&xzb[(size_t)ts * 4096 + c];
      rows[k][0] = bf2f(x.x); rows[k][1] = bf2f(x.y);
      rows[k][2] = bf2f(x.z); rows[k][3] = bf2f(x.w);
    }
  }
#pragma unroll
  for (int j = 0; j < 4; ++j) {
    float acc[4] = {cbv.x, cbv.y, cbv.z, cbv.w};
#pragma unroll
    for (int k = 0; k < 4; ++k) {
#pragma unroll
      for (int i = 0; i < 4; ++i)
        acc[i] = fmaf(rows[j + k][i], ((const float*)&wv[i])[k], acc[i]);
    }
    ushort4 o;
    o.x = f2bf(silu_f(acc[0]));
    o.y = f2bf(silu_f(acc[1]));
    o.z = f2bf(silu_f(acc[2]));
    o.w = f2bf(silu_f(acc[3]));
    *(ushort4*)&xcb[(size_t)(t0 + j) * D_INNER + c] = o;
  }
}

// Pass A: per-chunk cumulative dA product + local end state (h0 = 0).
__global__ __launch_bounds__(256) void scan_passA_kernel(
    const unsigned* __restrict__ dtu, const ushort_t* __restrict__ dbcb,
    const float* __restrict__ A_log,
    ushort_t* __restrict__ aprodb, ushort_t* __restrict__ hendb) {
  __shared__ float Bsh[CL][16];
  int c = blockIdx.x;
  int d = blockIdx.y * 256 + threadIdx.x;
  int t0 = c * CL;
  {
    int j = threadIdx.x;           // CL*16/4 = 64 ushort4 slots
    if (j < CL * 4) {
      int r = j >> 2, col = (j & 3) * 4;
      ushort4 v = *(const ushort4*)&dbcb[(size_t)(t0 + r) * DPROJ + DT_RANK + col];
      Bsh[r][col]     = bf2f(v.x);
      Bsh[r][col + 1] = bf2f(v.y);
      Bsh[r][col + 2] = bf2f(v.z);
      Bsh[r][col + 3] = bf2f(v.w);
    }
  }
  float Av[NSTATE], h[NSTATE], ap[NSTATE];
#pragma unroll
  for (int n = 0; n < NSTATE; ++n) {
    Av[n] = -expf(A_log[(size_t)d * NSTATE + n]) * LOG2E;
    h[n] = 0.f;
    ap[n] = 1.f;
  }
  __syncthreads();
#pragma unroll 2
  for (int tt = 0; tt < CL; ++tt) {
    unsigned p = dtu[(size_t)(t0 + tt) * D_INNER + d];
    float dtv = bf2f((ushort_t)(p & 0xffffu));
    float uv  = bf2f((ushort_t)(p >> 16));
    float du = dtv * uv;
#pragma unroll
    for (int n = 0; n < NSTATE; ++n) {
      float dA = exp2f(dtv * Av[n]);
      h[n] = fmaf(dA, h[n], du * Bsh[tt][n]);
      ap[n] *= dA;
    }
  }
  size_t base = ((size_t)c * D_INNER + d) * NSTATE;
  u8s oa, ob, ha, hb;
#pragma unroll
  for (int n = 0; n < 8; ++n) {
    oa[n] = f2bf(ap[n]);     ob[n] = f2bf(ap[n + 8]);
    ha[n] = f2bf(h[n]);      hb[n] = f2bf(h[n + 8]);
  }
  *(u8s*)&aprodb[base] = oa;     *(u8s*)&aprodb[base + 8] = ob;
  *(u8s*)&hendb[base]  = ha;     *(u8s*)&hendb[base + 8]  = hb;
}

// Pass B: carry across 128 chunks (bf16 state in/out).
__global__ __launch_bounds__(256) void scan_passB_kernel(
    const ushort_t* __restrict__ aprodb, ushort_t* __restrict__ hendb) {
  int tid = threadIdx.x;
  int lane = tid & 63;
  int wave = tid >> 6;
  int seg = lane >> 4;                       // 0..3
  int chain = blockIdx.x * 64 + wave * 16 + (lane & 15);
  const size_t stride = (size_t)D_INNER * NSTATE;
  float a[SCAN_CPS], e[SCAN_CPS];
  float P = 1.f, E = 0.f;
  int c0 = seg * SCAN_CPS;
#pragma unroll
  for (int j = 0; j < SCAN_CPS; ++j) {
    a[j] = bf2f(aprodb[(size_t)(c0 + j) * stride + chain]);
    e[j] = bf2f(hendb[(size_t)(c0 + j) * stride + chain]);
    E = fmaf(a[j], E, e[j]);
    P *= a[j];
  }
#pragma unroll
  for (int dstep = 1; dstep < SCAN_SEGS; dstep <<= 1) {
    float Pp = __shfl_up(P, dstep * 16);
    float Ep = __shfl_up(E, dstep * 16);
    if (seg >= dstep) { E = fmaf(P, Ep, E); P *= Pp; }
  }
  float Ex = __shfl_up(E, 16);
  if (seg == 0) Ex = 0.f;
  float h = Ex;
#pragma unroll
  for (int j = 0; j < SCAN_CPS; ++j) {
    hendb[(size_t)(c0 + j) * stride + chain] = f2bf(h);
    h = fmaf(a[j], h, e[j]);
  }
}

// Pass C: rescan from bf16 hin; y = (scan + u*D) * silu(z) -> bf16.
__global__ __launch_bounds__(256) void scan_passC_kernel(
    const unsigned* __restrict__ dtu, const ushort_t* __restrict__ dbcb,
    const float* __restrict__ A_log, const float* __restrict__ Dp,
    const ushort_t* __restrict__ xzb, const ushort_t* __restrict__ hinb,
    ushort_t* __restrict__ yb) {
  __shared__ float BCsh[CL][32];   // [tt][0..15]=B, [16..31]=C
  int c = blockIdx.x;
  int d = blockIdx.y * 256 + threadIdx.x;
  int t0 = c * CL;
  {
    int j = threadIdx.x;           // CL*32/4 = 128 ushort4 slots
    if (j < CL * 8) {
      int r = j >> 3, col = (j & 7) * 4;
      ushort4 v = *(const ushort4*)&dbcb[(size_t)(t0 + r) * DPROJ + DT_RANK + col];
      BCsh[r][col]     = bf2f(v.x);
      BCsh[r][col + 1] = bf2f(v.y);
      BCsh[r][col + 2] = bf2f(v.z);
      BCsh[r][col + 3] = bf2f(v.w);
    }
  }
  float Av[NSTATE], h[NSTATE];
  size_t base = ((size_t)c * D_INNER + d) * NSTATE;
  u8s h0 = *(const u8s*)&hinb[base];
  u8s h1 = *(const u8s*)&hinb[base + 8];
#pragma unroll
  for (int n = 0; n < NSTATE; ++n) {
    Av[n] = -expf(A_log[(size_t)d * NSTATE + n]) * LOG2E;
    h[n] = (n < 8) ? bf2f(h0[n & 7]) : bf2f(h1[n & 7]);
  }
  float Dv = Dp[d];
  __syncthreads();
#pragma unroll 2
  for (int tt = 0; tt < CL; ++tt) {
    unsigned p = dtu[(size_t)(t0 + tt) * D_INNER + d];
    float dtv = bf2f((ushort_t)(p & 0xffffu));
    float uv  = bf2f((ushort_t)(p >> 16));
    float du = dtv * uv;
    float yv = 0.f;
#pragma unroll
    for (int n = 0; n < NSTATE; ++n) {
      float dA = exp2f(dtv * Av[n]);
      h[n] = fmaf(dA, h[n], du * BCsh[tt][n]);
      yv = fmaf(h[n], BCsh[tt][16 + n], yv);
    }
    float zv = bf2f(xzb[(size_t)(t0 + tt) * 4096 + D_INNER + d]);
    yb[(size_t)(t0 + tt) * D_INNER + d] = f2bf((yv + uv * Dv) * silu_f(zv));
  }
}

extern "C" void kernel_launch(void* const* d_in, const int* in_sizes, int n_in,
                              void* d_out, int out_size, void* d_ws, size_t ws_size,
                              hipStream_t stream) {
  const float* h_in   = (const float*)d_in[0];
  const float* norm_w = (const float*)d_in[1];
  const float* in_w   = (const float*)d_in[2];
  const float* conv_w = (const float*)d_in[3];
  const float* conv_b = (const float*)d_in[4];
  const float* xp_w   = (const float*)d_in[5];
  const float* dt_w   = (const float*)d_in[6];
  const float* dt_b   = (const float*)d_in[7];
  const float* A_log  = (const float*)d_in[8];
  const float* Dp     = (const float*)d_in[9];
  const float* out_w  = (const float*)d_in[10];
  const float* normf  = (const float*)d_in[11];
  float* out = (float*)d_out;

  float* ws = (float*)d_ws;
  const size_t TD = (size_t)SEQ * D_MODEL;            // 2.10M
  const size_t TI = (size_t)SEQ * D_INNER;            // 4.19M
  const size_t ST = (size_t)NCH * D_INNER * NSTATE;   // 4.19M elements
  const size_t DB = (size_t)SEQ * DPROJ;
  const size_t INW = (size_t)2 * D_INNER * D_MODEL;
  const size_t XPW = (size_t)DPROJ * D_INNER;
  const size_t DTW = (size_t)D_INNER * DT_RANK;
  const size_t OUW = (size_t)D_MODEL * D_INNER;

  float* res = ws; ws += TD;
  ushort_t* pkb = (ushort_t*)ws; ws += 2 * TD;   // 4*TD ushorts (>= 16*DB)
  unsigned* dtu = (unsigned*)ws; ws += TI;
  ushort_t* us = (ushort_t*)ws;
  ushort_t* aprodb = us;  us += ST;
  ushort_t* hendb  = us;  us += ST;     // hin after passB
  ushort_t* hnb  = us;    us += TD;
  ushort_t* xzb  = us;    us += 2 * TI;
  ushort_t* xcb  = us;    us += TI;
  ushort_t* ybf  = us;    us += TI;
  ushort_t* dbcb = us;    us += DB;
  ushort_t* inwb = us;    us += 2 * INW;
  ushort_t* xpwb = us;    us += 2 * XPW;
  ushort_t* dtwb = us;    us += 2 * DTW;
  ushort_t* ouwb = us;    us += 2 * OUW;

  // convert ALL weights (both layers) in one dispatch
  {
    int n0 = (int)(2 * INW / 4), n1 = (int)(2 * XPW / 4);
    int n2 = (int)(2 * DTW / 4), n3 = (int)(2 * OUW / 4);
    int tot = n0 + n1 + n2 + n3;
    f2bf_all_kernel<<<(tot + 255) / 256, 256, 0, stream>>>(
        in_w, inwb, n0, xp_w, xpwb, n1, dt_w, dtwb, n2, out_w, ouwb, n3);
  }

  for (int i = 0; i < 2; ++i) {
    // residual update + rmsnorm; layer>0 consumes bf16 out_proj split-K=4 partials
    addrms_kernel<<<SEQ, 256, 0, stream>>>(
        h_in, i == 0 ? nullptr : pkb,
        i == 0 ? nullptr : res,
        norm_w + (size_t)i * D_MODEL, res, nullptr, hnb);
    // in_proj: [2048 x 1024] x [4096 x 1024]^T -> xzb (bf16)
    gemm_bt<1, false, 2><<<dim3(32, 16, 1), 256, 0, stream>>>(
        hnb, inwb + (size_t)i * INW, xzb, nullptr, nullptr,
        SEQ, 2 * D_INNER, D_MODEL, D_MODEL, D_MODEL, 2 * D_INNER);
    conv_silu_kernel<<<(int)(TI / 16 / 256), 256, 0, stream>>>(
        xzb, conv_w + (size_t)i * D_INNER * 4, conv_b + (size_t)i * D_INNER, xcb);
    // x_proj: split-K=16 -> pkb (bf16 partials), reduce -> dbcb (bf16)
    gemm_bt<16, true, 2><<<dim3(1, 16, 16), 256, 0, stream>>>(
        xcb, xpwb + (size_t)i * XPW, pkb, nullptr, nullptr,
        SEQ, DPROJ, D_INNER, D_INNER, D_INNER, DPROJ);
    reduceNb_kernel<<<(DB + 255) / 256, 256, 0, stream>>>(pkb, dbcb, (int)DB, 16);
    // dt_proj -> softplus -> packed (dt | u<<16) uint buffer
    gemm_bt<1, false, 3><<<dim3(16, 16, 1), 256, 0, stream>>>(
        dbcb, dtwb + (size_t)i * DTW, dtu, dt_b + (size_t)i * D_INNER, xcb,
        SEQ, D_INNER, DT_RANK, DPROJ, DT_RANK, D_INNER);
    // scan: A -> B -> C (3 dispatches, bf16 state)
    scan_passA_kernel<<<dim3(NCH, D_INNER / 256), 256, 0, stream>>>(
        dtu, dbcb, A_log + (size_t)i * D_INNER * NSTATE, aprodb, hendb);
    scan_passB_kernel<<<(D_INNER * NSTATE) / 64, 256, 0, stream>>>(aprodb, hendb);
    scan_passC_kernel<<<dim3(NCH, D_INNER / 256), 256, 0, stream>>>(
        dtu, dbcb, A_log + (size_t)i * D_INNER * NSTATE,
        Dp + (size_t)i * D_INNER, xzb, hendb, ybf);
    // out_proj: split-K=4 -> pkb (bf16 partials, 4 x TD)
    gemm_bt<4, false, 2><<<dim3(8, 16, 4), 256, 0, stream>>>(
        ybf, ouwb + (size_t)i * OUW, pkb, nullptr, nullptr,
        SEQ, D_MODEL, D_INNER, D_INNER, D_INNER, D_MODEL);
  }
  addrms_kernel<<<SEQ, 256, 0, stream>>>(
      h_in, pkb, res, normf, nullptr, out, nullptr);
}

// Round 14
// 340.260 us; speedup vs baseline: 3.0490x; 1.0259x over previous
//
#include <hip/hip_runtime.h>
#include <math.h>

#define D_MODEL 1024
#define D_INNER 2048
#define DPROJ   96      // DT_RANK + 2*D_STATE
#define DT_RANK 64
#define NSTATE  16
#define SEQ     2048
#define CL      16      // chunk length for scan
#define NCH     (SEQ/CL)            // 128
#define SCAN_SEGS 4
#define SCAN_CPS  (NCH / SCAN_SEGS) // 32 chunks per segment-lane
#define LOG2E   1.44269504088896340736f
#define TDC     ((size_t)SEQ * D_MODEL)   // compile-time TD for addrms p4 stride

typedef unsigned short ushort_t;
typedef short v8s __attribute__((ext_vector_type(8)));
typedef unsigned short u8s __attribute__((ext_vector_type(8)));
typedef float v4f __attribute__((ext_vector_type(4)));
typedef __attribute__((address_space(3))) unsigned int as3_u32;
typedef __attribute__((address_space(1))) unsigned int as1_u32;

__device__ __forceinline__ float silu_f(float x) { return x / (1.f + expf(-x)); }

__device__ __forceinline__ ushort_t f2bf(float f) {
  union { float f; unsigned u; } x; x.f = f;
  unsigned r = x.u + 0x7fffu + ((x.u >> 16) & 1u);  // RNE; inputs finite
  return (ushort_t)(r >> 16);
}
__device__ __forceinline__ float bf2f(ushort_t b) {
  union { unsigned u; float f; } x; x.u = ((unsigned)b) << 16; return x.f;
}

// async global->LDS, 16B per lane; lds dest = wave-uniform base + lane*16
__device__ __forceinline__ void gl_lds16(const ushort_t* g, ushort_t* l) {
  __builtin_amdgcn_global_load_lds((const as1_u32*)g, (as3_u32*)l, 16, 0, 0);
}

// x = (p4 ? sum of 4 bf16 partials : a) (+ b); res_out = x;
// xn = rmsnorm(x)*w -> f32 (xnf) and/or bf16 (xnb)
__global__ __launch_bounds__(256) void addrms_kernel(
    const float* __restrict__ a, const ushort_t* __restrict__ p4,
    const float* __restrict__ b,
    const float* __restrict__ w, float* __restrict__ res_out,
    float* __restrict__ xnf, ushort_t* __restrict__ xnb) {
  int t = blockIdx.x;
  int tid = threadIdx.x;
  float v[4];
  float ss = 0.f;
#pragma unroll
  for (int j = 0; j < 4; ++j) {
    int dcol = tid + j * 256;
    size_t off = (size_t)t * D_MODEL + dcol;
    float x;
    if (p4) {
      x = bf2f(p4[off]) + bf2f(p4[off + TDC]) +
          bf2f(p4[off + 2 * TDC]) + bf2f(p4[off + 3 * TDC]);
    } else {
      x = a[off];
    }
    if (b) x += b[off];
    v[j] = x;
    ss += x * x;
  }
#pragma unroll
  for (int off = 32; off > 0; off >>= 1) ss += __shfl_down(ss, off);
  __shared__ float red[4];
  __shared__ float rmsv;
  int wid = tid >> 6, lane = tid & 63;
  if (lane == 0) red[wid] = ss;
  __syncthreads();
  if (tid == 0) {
    float s = red[0] + red[1] + red[2] + red[3];
    rmsv = rsqrtf(s / (float)D_MODEL + 1e-5f);
  }
  __syncthreads();
  float r = rmsv;
#pragma unroll
  for (int j = 0; j < 4; ++j) {
    int dcol = tid + j * 256;
    if (res_out) res_out[(size_t)t * D_MODEL + dcol] = v[j];
    float xn = v[j] * r * w[dcol];
    if (xnf) xnf[(size_t)t * D_MODEL + dcol] = xn;
    if (xnb) xnb[(size_t)t * D_MODEL + dcol] = f2bf(xn);
  }
}

// single-dispatch f32->bf16 of all 4 weight tensors (both layers each)
__global__ __launch_bounds__(256) void f2bf_all_kernel(
    const float* __restrict__ s0, ushort_t* __restrict__ d0, int n0,
    const float* __restrict__ s1, ushort_t* __restrict__ d1, int n1,
    const float* __restrict__ s2, ushort_t* __restrict__ d2, int n2,
    const float* __restrict__ s3, ushort_t* __restrict__ d3, int n3) {
  int j = blockIdx.x * 256 + threadIdx.x;
  const float* s; ushort_t* d;
  if (j < n0) { s = s0; d = d0; }
  else {
    j -= n0;
    if (j < n1) { s = s1; d = d1; }
    else {
      j -= n1;
      if (j < n2) { s = s2; d = d2; }
      else {
        j -= n2;
        if (j >= n3) return;
        s = s3; d = d3;
      }
    }
  }
  float4 v = ((const float4*)s)[j];
  ushort4 o;
  o.x = f2bf(v.x); o.y = f2bf(v.y); o.z = f2bf(v.z); o.w = f2bf(v.w);
  ((ushort4*)d)[j] = o;
}

// ------------- bf16 MFMA GEMM (NT): C[m,n] = sum_k A[m,k]*B[n,k] -------------
// m97 structure + double-buffered prefetch; one __syncthreads per K-step.
// XCD-aware bijective block swizzle (m204). SPLITK>1: partials at z*M*ldc.
// EPI: 0 = f32 out, 1 = softplus(acc+bias[col]) -> bf16, 2 = bf16,
//      3 = pack( bf16(softplus(acc+bias)) | upack[idx]<<16 ) -> uint out.
template <int SPLITK, bool CLAMPN, int EPI>
__global__ __launch_bounds__(256) void gemm_bt(
    const ushort_t* __restrict__ A, const ushort_t* __restrict__ B,
    void* __restrict__ Cv, const float* __restrict__ bias,
    const ushort_t* __restrict__ upack,
    int M, int N, int K, int lda, int ldb, int ldc) {
  __shared__ ushort_t As[2][128 * 32];
  __shared__ ushort_t Bs[2][128 * 32];
  int tid = threadIdx.x;

  // bijective XCD swizzle of the flattened block id
  int gx = gridDim.x, gy = gridDim.y;
  int nwg = gx * gy * gridDim.z;
  int phys = blockIdx.x + gx * (blockIdx.y + gy * blockIdx.z);
  int q = nwg >> 3, r = nwg & 7;
  int xcd = phys & 7, idx8 = phys >> 3;
  int lbid = (xcd < r ? xcd * (q + 1) : r * (q + 1) + (xcd - r) * q) + idx8;
  int bx = lbid % gx, by = (lbid / gx) % gy, bz = lbid / (gx * gy);

  int bm = by * 128;
  int bn = bx * 128;
  int kchunk = K / SPLITK;
  int k0 = bz * kchunk;
  int nk = kchunk / 32;

  int lane = tid & 63, wid = tid >> 6;
  int wr = wid >> 1, wc = wid & 1;
  int lr = lane & 15;
  int ko = (lane >> 4) * 8;

  int rs0 = wid * 16 + (lane >> 2);
  int segc = (lane & 3) * 8;

  auto stage = [&](int buf, int kt) {
#pragma unroll
    for (int s = 0; s < 2; ++s) {
      int r2 = s * 64 + rs0;
      int cc = kt + segc;
      gl_lds16(A + (size_t)(bm + r2) * lda + cc, &As[buf][s * 2048 + wid * 512]);
      int bc = bn + r2;
      if (CLAMPN) bc = min(bc, N - 1);   // in-bounds; junk cols never stored
      gl_lds16(B + (size_t)bc * ldb + cc, &Bs[buf][s * 2048 + wid * 512]);
    }
  };

  v4f acc[4][4] = {};

  stage(0, k0);
  __syncthreads();
  int cur = 0;
  for (int it = 0; it < nk; ++it) {
    if (it + 1 < nk) stage(cur ^ 1, k0 + (it + 1) * 32);
    v8s a[4], b[4];
#pragma unroll
    for (int m = 0; m < 4; ++m)
      a[m] = *(const v8s*)&As[cur][(wr * 64 + m * 16 + lr) * 32 + ko];
#pragma unroll
    for (int n = 0; n < 4; ++n)
      b[n] = *(const v8s*)&Bs[cur][(wc * 64 + n * 16 + lr) * 32 + ko];
#pragma unroll
    for (int m = 0; m < 4; ++m)
#pragma unroll
      for (int n = 0; n < 4; ++n)
        acc[m][n] = __builtin_amdgcn_mfma_f32_16x16x32_bf16(a[m], b[n], acc[m][n], 0, 0, 0);
    __syncthreads();
    cur ^= 1;
  }

  float* Cf = (float*)Cv;
  ushort_t* Cb = (ushort_t*)Cv;
  unsigned* Cu = (unsigned*)Cv;
  size_t zoff = (SPLITK > 1) ? (size_t)bz * (size_t)M * (size_t)ldc : 0;

#pragma unroll
  for (int m = 0; m < 4; ++m) {
#pragma unroll
    for (int n = 0; n < 4; ++n) {
      int gc = bn + wc * 64 + n * 16 + lr;
      if (gc >= N) continue;
      int gr0 = bm + wr * 64 + m * 16 + (lane >> 4) * 4;
      float bv = (EPI == 1 || EPI == 3) ? bias[gc] : 0.f;
#pragma unroll
      for (int j = 0; j < 4; ++j) {
        float val = acc[m][n][j];
        size_t idx = zoff + (size_t)(gr0 + j) * ldc + gc;
        if (EPI == 0) {
          Cf[idx] = val;
        } else if (EPI == 1) {
          float x = val + bv;
          x = fmaxf(x, 0.f) + log1pf(expf(-fabsf(x)));
          Cb[idx] = f2bf(x);
        } else if (EPI == 2) {
          Cb[idx] = f2bf(val);
        } else {
          float x = val + bv;
          x = fmaxf(x, 0.f) + log1pf(expf(-fabsf(x)));
          Cu[idx] = (unsigned)f2bf(x) | ((unsigned)upack[idx] << 16);
        }
      }
    }
  }
}

// ---------- fused conv_silu + x_proj K-slice GEMM ----------
// grid (1, 16 M-tiles, 16 K-slices). Block (by,bz):
//  phase 1: conv+silu for t in [bm,bm+128), c in [bz*128,bz*128+128)
//           -> LDS A-tile [128][136] (padded, 16B rows) AND global xcb.
//  phase 2: 128x96 GEMM vs xpwb rows, K-slice of 128, A from resident LDS,
//           B double-buffered via global_load_lds; bf16 partial out.
__global__ __launch_bounds__(256) void convxproj_kernel(
    const ushort_t* __restrict__ xzb, const float* __restrict__ cw,
    const float* __restrict__ cb, const ushort_t* __restrict__ Bw,
    ushort_t* __restrict__ xcb, ushort_t* __restrict__ pkb) {
  __shared__ ushort_t As[128][136];   // 272B rows: 16B-aligned, 2-way banks
  __shared__ ushort_t Bs[2][128 * 32];
  int tid = threadIdx.x;
  int bm = blockIdx.y * 128;
  int c0s = blockIdx.z * 128;         // channel / K-slice offset
  int k0 = c0s;

  // ---- phase 1: conv ----
  {
    int quad = tid & 31;              // 4 channels each
    int tg = tid >> 5;                // 8 groups x 16 t
    int cc = c0s + quad * 4;
    int tbase = bm + tg * 16;
    float4 cbv = *(const float4*)&cb[cc];
    float4 wv[4];
#pragma unroll
    for (int i = 0; i < 4; ++i) wv[i] = *(const float4*)&cw[(cc + i) * 4];
    float rw[4][4];                   // ring of last 4 rows (compile-time idx)
#pragma unroll
    for (int p = 0; p < 3; ++p) {
      int ts = tbase - 3 + p;
      if (ts < 0) {
        rw[p][0] = rw[p][1] = rw[p][2] = rw[p][3] = 0.f;
      } else {
        ushort4 x = *(const ushort4*)&xzb[(size_t)ts * 4096 + cc];
        rw[p][0] = bf2f(x.x); rw[p][1] = bf2f(x.y);
        rw[p][2] = bf2f(x.z); rw[p][3] = bf2f(x.w);
      }
    }
#pragma unroll
    for (int j = 0; j < 16; ++j) {
      int t = tbase + j;
      {
        ushort4 x = *(const ushort4*)&xzb[(size_t)t * 4096 + cc];
        rw[(3 + j) & 3][0] = bf2f(x.x); rw[(3 + j) & 3][1] = bf2f(x.y);
        rw[(3 + j) & 3][2] = bf2f(x.z); rw[(3 + j) & 3][3] = bf2f(x.w);
      }
      float acc[4] = {cbv.x, cbv.y, cbv.z, cbv.w};
#pragma unroll
      for (int k = 0; k < 4; ++k) {
#pragma unroll
        for (int i = 0; i < 4; ++i)
          acc[i] = fmaf(rw[(j + k) & 3][i], ((const float*)&wv[i])[k], acc[i]);
      }
      ushort4 o;
      o.x = f2bf(silu_f(acc[0]));
      o.y = f2bf(silu_f(acc[1]));
      o.z = f2bf(silu_f(acc[2]));
      o.w = f2bf(silu_f(acc[3]));
      *(ushort4*)&As[tg * 16 + j][quad * 4] = o;
      *(ushort4*)&xcb[(size_t)t * D_INNER + cc] = o;
    }
  }

  // ---- phase 2: GEMM (A resident in LDS) ----
  int lane = tid & 63, wid = tid >> 6;
  int wr = wid >> 1, wc = wid & 1;
  int lr = lane & 15;
  int ko = (lane >> 4) * 8;
  int rs0 = wid * 16 + (lane >> 2);
  int segc = (lane & 3) * 8;

  auto stageB = [&](int buf, int it) {
#pragma unroll
    for (int s = 0; s < 2; ++s) {
      int r2 = s * 64 + rs0;
      int bc = min(r2, DPROJ - 1);
      int cc2 = k0 + it * 32 + segc;
      gl_lds16(Bw + (size_t)bc * D_INNER + cc2, &Bs[buf][s * 2048 + wid * 512]);
    }
  };

  v4f acc[4][4] = {};
  stageB(0, 0);
  __syncthreads();     // covers conv As writes + Bs[0]
  int cur = 0;
  for (int it = 0; it < 4; ++it) {
    if (it + 1 < 4) stageB(cur ^ 1, it + 1);
    v8s a[4], b[4];
#pragma unroll
    for (int m = 0; m < 4; ++m)
      a[m] = *(const v8s*)&As[wr * 64 + m * 16 + lr][it * 32 + ko];
#pragma unroll
    for (int n = 0; n < 4; ++n)
      b[n] = *(const v8s*)&Bs[cur][(wc * 64 + n * 16 + lr) * 32 + ko];
#pragma unroll
    for (int m = 0; m < 4; ++m)
#pragma unroll
      for (int n = 0; n < 4; ++n)
        acc[m][n] = __builtin_amdgcn_mfma_f32_16x16x32_bf16(a[m], b[n], acc[m][n], 0, 0, 0);
    __syncthreads();
    cur ^= 1;
  }

  size_t zoff = (size_t)blockIdx.z * (size_t)SEQ * DPROJ;
#pragma unroll
  for (int m = 0; m < 4; ++m) {
#pragma unroll
    for (int n = 0; n < 4; ++n) {
      int gc = wc * 64 + n * 16 + lr;
      if (gc >= DPROJ) continue;
      int gr0 = bm + wr * 64 + m * 16 + (lane >> 4) * 4;
#pragma unroll
      for (int j = 0; j < 4; ++j)
        pkb[zoff + (size_t)(gr0 + j) * DPROJ + gc] = f2bf(acc[m][n][j]);
    }
  }
}

// outb[idx] = bf16( sum_p bf2f(part[idx + p*sz]) )
__global__ __launch_bounds__(256) void reduceNb_kernel(
    const ushort_t* __restrict__ part, ushort_t* __restrict__ outb,
    int sz, int nparts) {
  int idx = blockIdx.x * 256 + threadIdx.x;
  if (idx >= sz) return;
  float s = 0.f;
  for (int p = 0; p < nparts; ++p) s += bf2f(part[idx + (size_t)p * sz]);
  outb[idx] = f2bf(s);
}

// Pass A: per-chunk cumulative dA product + local end state (h0 = 0).
__global__ __launch_bounds__(256) void scan_passA_kernel(
    const unsigned* __restrict__ dtu, const ushort_t* __restrict__ dbcb,
    const float* __restrict__ A_log,
    ushort_t* __restrict__ aprodb, ushort_t* __restrict__ hendb) {
  __shared__ float Bsh[CL][16];
  int c = blockIdx.x;
  int d = blockIdx.y * 256 + threadIdx.x;
  int t0 = c * CL;
  {
    int j = threadIdx.x;           // CL*16/4 = 64 ushort4 slots
    if (j < CL * 4) {
      int r = j >> 2, col = (j & 3) * 4;
      ushort4 v = *(const ushort4*)&dbcb[(size_t)(t0 + r) * DPROJ + DT_RANK + col];
      Bsh[r][col]     = bf2f(v.x);
      Bsh[r][col + 1] = bf2f(v.y);
      Bsh[r][col + 2] = bf2f(v.z);
      Bsh[r][col + 3] = bf2f(v.w);
    }
  }
  float Av[NSTATE], h[NSTATE], ap[NSTATE];
#pragma unroll
  for (int n = 0; n < NSTATE; ++n) {
    Av[n] = -expf(A_log[(size_t)d * NSTATE + n]) * LOG2E;
    h[n] = 0.f;
    ap[n] = 1.f;
  }
  __syncthreads();
#pragma unroll 2
  for (int tt = 0; tt < CL; ++tt) {
    unsigned p = dtu[(size_t)(t0 + tt) * D_INNER + d];
    float dtv = bf2f((ushort_t)(p & 0xffffu));
    float uv  = bf2f((ushort_t)(p >> 16));
    float du = dtv * uv;
#pragma unroll
    for (int n = 0; n < NSTATE; ++n) {
      float dA = exp2f(dtv * Av[n]);
      h[n] = fmaf(dA, h[n], du * Bsh[tt][n]);
      ap[n] *= dA;
    }
  }
  size_t base = ((size_t)c * D_INNER + d) * NSTATE;
  u8s oa, ob, ha, hb;
#pragma unroll
  for (int n = 0; n < 8; ++n) {
    oa[n] = f2bf(ap[n]);     ob[n] = f2bf(ap[n + 8]);
    ha[n] = f2bf(h[n]);      hb[n] = f2bf(h[n + 8]);
  }
  *(u8s*)&aprodb[base] = oa;     *(u8s*)&aprodb[base + 8] = ob;
  *(u8s*)&hendb[base]  = ha;     *(u8s*)&hendb[base + 8]  = hb;
}

// Pass B: carry across 128 chunks (bf16 state in/out).
__global__ __launch_bounds__(256) void scan_passB_kernel(
    const ushort_t* __restrict__ aprodb, ushort_t* __restrict__ hendb) {
  int tid = threadIdx.x;
  int lane = tid & 63;
  int wave = tid >> 6;
  int seg = lane >> 4;                       // 0..3
  int chain = blockIdx.x * 64 + wave * 16 + (lane & 15);
  const size_t stride = (size_t)D_INNER * NSTATE;
  float a[SCAN_CPS], e[SCAN_CPS];
  float P = 1.f, E = 0.f;
  int c0 = seg * SCAN_CPS;
#pragma unroll
  for (int j = 0; j < SCAN_CPS; ++j) {
    a[j] = bf2f(aprodb[(size_t)(c0 + j) * stride + chain]);
    e[j] = bf2f(hendb[(size_t)(c0 + j) * stride + chain]);
    E = fmaf(a[j], E, e[j]);
    P *= a[j];
  }
#pragma unroll
  for (int dstep = 1; dstep < SCAN_SEGS; dstep <<= 1) {
    float Pp = __shfl_up(P, dstep * 16);
    float Ep = __shfl_up(E, dstep * 16);
    if (seg >= dstep) { E = fmaf(P, Ep, E); P *= Pp; }
  }
  float Ex = __shfl_up(E, 16);
  if (seg == 0) Ex = 0.f;
  float h = Ex;
#pragma unroll
  for (int j = 0; j < SCAN_CPS; ++j) {
    hendb[(size_t)(c0 + j) * stride + chain] = f2bf(h);
    h = fmaf(a[j], h, e[j]);
  }
}

// Pass C: rescan from bf16 hin; y = (scan + u*D) * silu(z) -> bf16.
__global__ __launch_bounds__(256) void scan_passC_kernel(
    const unsigned* __restrict__ dtu, const ushort_t* __restrict__ dbcb,
    const float* __restrict__ A_log, const float* __restrict__ Dp,
    const ushort_t* __restrict__ xzb, const ushort_t* __restrict__ hinb,
    ushort_t* __restrict__ yb) {
  __shared__ float BCsh[CL][32];   // [tt][0..15]=B, [16..31]=C
  int c = blockIdx.x;
  int d = blockIdx.y * 256 + threadIdx.x;
  int t0 = c * CL;
  {
    int j = threadIdx.x;           // CL*32/4 = 128 ushort4 slots
    if (j < CL * 8) {
      int r = j >> 3, col = (j & 7) * 4;
      ushort4 v = *(const ushort4*)&dbcb[(size_t)(t0 + r) * DPROJ + DT_RANK + col];
      BCsh[r][col]     = bf2f(v.x);
      BCsh[r][col + 1] = bf2f(v.y);
      BCsh[r][col + 2] = bf2f(v.z);
      BCsh[r][col + 3] = bf2f(v.w);
    }
  }
  float Av[NSTATE], h[NSTATE];
  size_t base = ((size_t)c * D_INNER + d) * NSTATE;
  u8s h0 = *(const u8s*)&hinb[base];
  u8s h1 = *(const u8s*)&hinb[base + 8];
#pragma unroll
  for (int n = 0; n < NSTATE; ++n) {
    Av[n] = -expf(A_log[(size_t)d * NSTATE + n]) * LOG2E;
    h[n] = (n < 8) ? bf2f(h0[n & 7]) : bf2f(h1[n & 7]);
  }
  float Dv = Dp[d];
  __syncthreads();
#pragma unroll 2
  for (int tt = 0; tt < CL; ++tt) {
    unsigned p = dtu[(size_t)(t0 + tt) * D_INNER + d];
    float dtv = bf2f((ushort_t)(p & 0xffffu));
    float uv  = bf2f((ushort_t)(p >> 16));
    float du = dtv * uv;
    float yv = 0.f;
#pragma unroll
    for (int n = 0; n < NSTATE; ++n) {
      float dA = exp2f(dtv * Av[n]);
      h[n] = fmaf(dA, h[n], du * BCsh[tt][n]);
      yv = fmaf(h[n], BCsh[tt][16 + n], yv);
    }
    float zv = bf2f(xzb[(size_t)(t0 + tt) * 4096 + D_INNER + d]);
    yb[(size_t)(t0 + tt) * D_INNER + d] = f2bf((yv + uv * Dv) * silu_f(zv));
  }
}

extern "C" void kernel_launch(void* const* d_in, const int* in_sizes, int n_in,
                              void* d_out, int out_size, void* d_ws, size_t ws_size,
                              hipStream_t stream) {
  const float* h_in   = (const float*)d_in[0];
  const float* norm_w = (const float*)d_in[1];
  const float* in_w   = (const float*)d_in[2];
  const float* conv_w = (const float*)d_in[3];
  const float* conv_b = (const float*)d_in[4];
  const float* xp_w   = (const float*)d_in[5];
  const float* dt_w   = (const float*)d_in[6];
  const float* dt_b   = (const float*)d_in[7];
  const float* A_log  = (const float*)d_in[8];
  const float* Dp     = (const float*)d_in[9];
  const float* out_w  = (const float*)d_in[10];
  const float* normf  = (const float*)d_in[11];
  float* out = (float*)d_out;

  float* ws = (float*)d_ws;
  const size_t TD = (size_t)SEQ * D_MODEL;            // 2.10M
  const size_t TI = (size_t)SEQ * D_INNER;            // 4.19M
  const size_t ST = (size_t)NCH * D_INNER * NSTATE;   // 4.19M elements
  const size_t DB = (size_t)SEQ * DPROJ;
  const size_t INW = (size_t)2 * D_INNER * D_MODEL;
  const size_t XPW = (size_t)DPROJ * D_INNER;
  const size_t DTW = (size_t)D_INNER * DT_RANK;
  const size_t OUW = (size_t)D_MODEL * D_INNER;

  float* res = ws; ws += TD;
  ushort_t* pkb = (ushort_t*)ws; ws += 2 * TD;   // 4*TD ushorts (>= 16*DB)
  unsigned* dtu = (unsigned*)ws; ws += TI;
  ushort_t* us = (ushort_t*)ws;
  ushort_t* aprodb = us;  us += ST;
  ushort_t* hendb  = us;  us += ST;     // hin after passB
  ushort_t* hnb  = us;    us += TD;
  ushort_t* xzb  = us;    us += 2 * TI;
  ushort_t* xcb  = us;    us += TI;
  ushort_t* ybf  = us;    us += TI;
  ushort_t* dbcb = us;    us += DB;
  ushort_t* inwb = us;    us += 2 * INW;
  ushort_t* xpwb = us;    us += 2 * XPW;
  ushort_t* dtwb = us;    us += 2 * DTW;
  ushort_t* ouwb = us;    us += 2 * OUW;

  // convert ALL weights (both layers) in one dispatch
  {
    int n0 = (int)(2 * INW / 4), n1 = (int)(2 * XPW / 4);
    int n2 = (int)(2 * DTW / 4), n3 = (int)(2 * OUW / 4);
    int tot = n0 + n1 + n2 + n3;
    f2bf_all_kernel<<<(tot + 255) / 256, 256, 0, stream>>>(
        in_w, inwb, n0, xp_w, xpwb, n1, dt_w, dtwb, n2, out_w, ouwb, n3);
  }

  for (int i = 0; i < 2; ++i) {
    // residual update + rmsnorm; layer>0 consumes bf16 out_proj split-K=4 partials
    addrms_kernel<<<SEQ, 256, 0, stream>>>(
        h_in, i == 0 ? nullptr : pkb,
        i == 0 ? nullptr : res,
        norm_w + (size_t)i * D_MODEL, res, nullptr, hnb);
    // in_proj: [2048 x 1024] x [4096 x 1024]^T -> xzb (bf16)
    gemm_bt<1, false, 2><<<dim3(32, 16, 1), 256, 0, stream>>>(
        hnb, inwb + (size_t)i * INW, xzb, nullptr, nullptr,
        SEQ, 2 * D_INNER, D_MODEL, D_MODEL, D_MODEL, 2 * D_INNER);
    // fused conv+silu (-> xcb) + x_proj K-slice GEMM (-> pkb bf16 partials x16)
    convxproj_kernel<<<dim3(1, 16, 16), 256, 0, stream>>>(
        xzb, conv_w + (size_t)i * D_INNER * 4, conv_b + (size_t)i * D_INNER,
        xpwb + (size_t)i * XPW, xcb, pkb);
    reduceNb_kernel<<<(DB + 255) / 256, 256, 0, stream>>>(pkb, dbcb, (int)DB, 16);
    // dt_proj -> softplus -> packed (dt | u<<16) uint buffer
    gemm_bt<1, false, 3><<<dim3(16, 16, 1), 256, 0, stream>>>(
        dbcb, dtwb + (size_t)i * DTW, dtu, dt_b + (size_t)i * D_INNER, xcb,
        SEQ, D_INNER, DT_RANK, DPROJ, DT_RANK, D_INNER);
    // scan: A -> B -> C (3 dispatches, bf16 state)
    scan_passA_kernel<<<dim3(NCH, D_INNER / 256), 256, 0, stream>>>(
        dtu, dbcb, A_log + (size_t)i * D_INNER * NSTATE, aprodb, hendb);
    scan_passB_kernel<<<(D_INNER * NSTATE) / 64, 256, 0, stream>>>(aprodb, hendb);
    scan_passC_kernel<<<dim3(NCH, D_INNER / 256), 256, 0, stream>>>(
        dtu, dbcb, A_log + (size_t)i * D_INNER * NSTATE,
        Dp + (size_t)i * D_INNER, xzb, hendb, ybf);
    // out_proj: split-K=4 -> pkb (bf16 partials, 4 x TD)
    gemm_bt<4, false, 2><<<dim3(8, 16, 4), 256, 0, stream>>>(
        ybf, ouwb + (size_t)i * OUW, pkb, nullptr, nullptr,
        SEQ, D_MODEL, D_INNER, D_INNER, D_INNER, D_MODEL);
  }
  addrms_kernel<<<SEQ, 256, 0, stream>>>(
      h_in, pkb, res, normf, nullptr, out, nullptr);
}